// Round 3
// baseline (851.887 us; speedup 1.0000x reference)
//
#include <hip/hip_runtime.h>
#include <math.h>

// Shapes (fixed by reference setup_inputs)
constexpr int NB  = 2048;   // batch (graphs)
constexpr int NN  = 60;     // nodes per graph
constexpr int DD  = 6;      // max degree slots
constexpr int AF  = 37;     // atom features
constexpr int BFD = 6;      // bond features
constexpr int HH  = 128;    // hidden
constexpr int CC  = 12;     // classes
constexpr int IN1 = AF + BFD;   // 43
constexpr int IN2 = HH + BFD;   // 134
constexpr int IN1P = 44;        // padded stride (16B-aligned rows)
constexpr int IN2P = 136;
constexpr int T   = 512;        // threads per block (8 waves)
constexpr int MAXT = 16;        // degree-pure tiles of 8

// Degree-pure conv: each lane computes 8 nodes x 2 h-cols. One weight stream
// per tile reused 16x in registers. f-loads split in two groups of 4 to cap
// live VGPRs (~16 fewer peak); __launch_bounds__(512,2) allows 256 VGPRs.
template<int IN, int INP>
__device__ __forceinline__ void conv_tiles(
    const float* __restrict__ W,     // (D,IN,H) global
    const float* __restrict__ bias,  // (D,H) global
    const float* sFeat,              // LDS, stride INP, 16B-aligned rows
    float* sOut,                     // LDS, stride HH
    const int* sTileNode, const int* sTileDeg, int nT,
    int wv, int lane)
{
    const int h0 = lane, h1 = lane + 64;
    for (int tile = wv; tile < nT; tile += 8) {
        const int dg = sTileDeg[tile];
        int nd[8], nr[8];
        #pragma unroll
        for (int j = 0; j < 8; ++j) nd[j] = sTileNode[tile * 8 + j];
        const int n0 = nd[0];
        #pragma unroll
        for (int j = 0; j < 8; ++j) nr[j] = (nd[j] >= 0) ? nd[j] : n0;
        const float* Wr = W + (size_t)dg * IN * HH;
        const float bb0 = bias[dg * HH + h0];
        const float bb1 = bias[dg * HH + h1];
        float a0[8], a1[8];
        #pragma unroll
        for (int j = 0; j < 8; ++j) { a0[j] = bb0; a1[j] = bb1; }

        constexpr int KM = IN & ~3;
        for (int ic = 0; ic < KM; ic += 4) {
            float w0[4], w1[4];
            #pragma unroll
            for (int k = 0; k < 4; ++k) {
                w0[k] = Wr[(ic + k) * HH + h0];
                w1[k] = Wr[(ic + k) * HH + h1];
            }
            #pragma unroll
            for (int jh = 0; jh < 2; ++jh) {
                float4 f[4];
                #pragma unroll
                for (int j = 0; j < 4; ++j)
                    f[j] = *(const float4*)(sFeat + nr[jh * 4 + j] * INP + ic);
                #pragma unroll
                for (int j = 0; j < 4; ++j) {
                    const int jj = jh * 4 + j;
                    a0[jj] = fmaf(f[j].x, w0[0], a0[jj]);
                    a0[jj] = fmaf(f[j].y, w0[1], a0[jj]);
                    a0[jj] = fmaf(f[j].z, w0[2], a0[jj]);
                    a0[jj] = fmaf(f[j].w, w0[3], a0[jj]);
                    a1[jj] = fmaf(f[j].x, w1[0], a1[jj]);
                    a1[jj] = fmaf(f[j].y, w1[1], a1[jj]);
                    a1[jj] = fmaf(f[j].z, w1[2], a1[jj]);
                    a1[jj] = fmaf(f[j].w, w1[3], a1[jj]);
                }
            }
        }
        for (int i = KM; i < IN; ++i) {   // remainder (3 for IN1, 2 for IN2)
            const float w0v = Wr[i * HH + h0];
            const float w1v = Wr[i * HH + h1];
            #pragma unroll
            for (int j = 0; j < 8; ++j) {
                const float fv = sFeat[nr[j] * INP + i];
                a0[j] = fmaf(fv, w0v, a0[j]);
                a1[j] = fmaf(fv, w1v, a1[j]);
            }
        }
        #pragma unroll
        for (int j = 0; j < 8; ++j) {
            if (nd[j] >= 0) {   // wave-uniform guard (skip duplicate pads)
                sOut[nd[j] * HH + h0] = fmaxf(a0[j], 0.f);
                sOut[nd[j] * HH + h1] = fmaxf(a1[j], 0.f);
            }
        }
    }
}

__global__ __launch_bounds__(T, 2) void ngfp_kernel(
    const float* __restrict__ atoms,  // (B,N,AF)
    const float* __restrict__ bonds,  // (B,N,D,BFD)
    const int*   __restrict__ edges,  // (B,N,D), -1 pad
    const float* __restrict__ W1,     // (D,IN1,H)
    const float* __restrict__ b1,     // (D,H)
    const float* __restrict__ W2,     // (D,IN2,H)
    const float* __restrict__ b2,     // (D,H)
    const float* __restrict__ Wo,     // (IN2,H)
    const float* __restrict__ bo,     // (H)
    const float* __restrict__ Wfc,    // (H,C)
    const float* __restrict__ bfc,    // (C)
    float* __restrict__ out)          // (B,C)
{
    __shared__ float sA[NN * HH];          // 30720 B
    __shared__ float sU[IN2 * HH];         // 68608 B (union region)
    __shared__ float sBsum[NN * BFD];
    __shared__ int   sEdges[NN * DD];
    __shared__ int   sDeg[NN];
    __shared__ int   sCnt[8];
    __shared__ int   sTStart[8];
    __shared__ int   sTileNode[MAXT * 8];
    __shared__ int   sTileDeg[MAXT];
    __shared__ int   sNumTiles;
    __shared__ float sPart[8 * HH];

    float* const sFeat = sU;
    float* const sX    = sU + NN * IN2P;
    float* const sWo   = sU;               // alias, used after conv phases

    const int b = blockIdx.x;
    const int t = threadIdx.x;
    const int wv = t >> 6;
    const int lane = t & 63;
    const int h0 = lane, h1 = lane + 64;

    // ---- Phase 0: stage edges, atoms, bond-sums ----
    for (int i = t; i < NN * DD; i += T) sEdges[i] = edges[b * NN * DD + i];
    for (int i = t; i < NN * AF; i += T) sA[i] = atoms[b * NN * AF + i];
    for (int i = t; i < NN * BFD; i += T) {
        int n = i / BFD, f = i - n * BFD;
        const float* bp = bonds + ((size_t)(b * NN + n) * DD) * BFD + f;
        float s = 0.f;
        #pragma unroll
        for (int d = 0; d < DD; ++d) s += bp[d * BFD];
        sBsum[i] = s;
    }
    __syncthreads();

    // ---- Phase 0b: degree + feat1 build ----
    if (t < NN) {
        int dg = 0;
        #pragma unroll
        for (int d = 0; d < DD; ++d) dg += (sEdges[t * DD + d] != -1) ? 1 : 0;
        sDeg[t] = dg;
    }
    for (int idx = t; idx < NN * IN1; idx += T) {
        int n = idx / IN1, i = idx - n * IN1;
        float v;
        if (i < AF) {
            v = sA[n * AF + i];
            #pragma unroll
            for (int d = 0; d < DD; ++d) {
                int e = sEdges[n * DD + d];
                if (e >= 0) v += sA[e * AF + i];
            }
        } else {
            v = sBsum[n * BFD + (i - AF)];
        }
        sFeat[n * IN1P + i] = v;
    }
    __syncthreads();

    // ---- Phase 0c: degree-pure tiles of 8 (counting sort, pad -1) ----
    if (t < 7) {
        int c = 0;
        for (int n = 0; n < NN; ++n) c += (sDeg[n] == t) ? 1 : 0;
        sCnt[t] = c;
    }
    __syncthreads();
    if (t == 0) {
        int nt = 0;
        for (int d = 0; d < 7; ++d) { sTStart[d] = nt; nt += (sCnt[d] + 7) / 8; }
        sNumTiles = nt;
    }
    __syncthreads();
    if (t < 7) {
        const int d = t;
        int tile = sTStart[d], c = 0;
        for (int n = 0; n < NN; ++n) {
            if (sDeg[n] == d) {
                sTileNode[tile * 8 + (c & 7)] = n;
                ++c;
                if ((c & 7) == 0) ++tile;
            }
        }
        if ((c & 7) != 0) {
            for (int j = (c & 7); j < 8; ++j) sTileNode[tile * 8 + j] = -1;
        }
        const int tend = sTStart[d] + (sCnt[d] + 7) / 8;
        for (int tt = sTStart[d]; tt < tend; ++tt) sTileDeg[tt] = d;
    }
    __syncthreads();
    const int nT = sNumTiles;

    // ---- Phase 1: conv1 -> sA ----
    conv_tiles<IN1, IN1P>(W1, b1, sFeat, sA, sTileNode, sTileDeg, nT, wv, lane);
    __syncthreads();

    // ---- Phase 2: pool1 -> sX ----
    for (int idx = t; idx < NN * (HH / 4); idx += T) {
        int n = idx >> 5, k = idx & 31;
        float4 m;
        if (sDeg[n] == 0) {
            m = make_float4(0.f, 0.f, 0.f, 0.f);
        } else {
            m = *(const float4*)(sA + n * HH + 4 * k);
            #pragma unroll
            for (int d = 0; d < DD; ++d) {
                int e = sEdges[n * DD + d];
                if (e >= 0) {
                    float4 v = *(const float4*)(sA + e * HH + 4 * k);
                    m.x = fmaxf(m.x, v.x); m.y = fmaxf(m.y, v.y);
                    m.z = fmaxf(m.z, v.z); m.w = fmaxf(m.w, v.w);
                }
            }
        }
        *(float4*)(sX + n * HH + 4 * k) = m;
    }
    __syncthreads();

    // ---- Phase 3a: feat2 = (self+nbr sums of X2 | bsum), stride IN2P ----
    for (int idx = t; idx < NN * (HH / 4); idx += T) {
        int n = idx >> 5, k = idx & 31;
        float4 v = *(const float4*)(sX + n * HH + 4 * k);
        #pragma unroll
        for (int d = 0; d < DD; ++d) {
            int e = sEdges[n * DD + d];
            if (e >= 0) {
                float4 u = *(const float4*)(sX + e * HH + 4 * k);
                v.x += u.x; v.y += u.y; v.z += u.z; v.w += u.w;
            }
        }
        *(float4*)(sFeat + n * IN2P + 4 * k) = v;
    }
    for (int idx = t; idx < NN * BFD; idx += T) {
        int n = idx / BFD, jb = idx - n * BFD;
        sFeat[n * IN2P + HH + jb] = sBsum[idx];
    }
    __syncthreads();

    // ---- Phase 3b: conv2 -> sX ----
    conv_tiles<IN2, IN2P>(W2, b2, sFeat, sX, sTileNode, sTileDeg, nT, wv, lane);
    __syncthreads();

    // ---- Phase 4: pool2 -> sA ----
    for (int idx = t; idx < NN * (HH / 4); idx += T) {
        int n = idx >> 5, k = idx & 31;
        float4 m;
        if (sDeg[n] == 0) {
            m = make_float4(0.f, 0.f, 0.f, 0.f);
        } else {
            m = *(const float4*)(sX + n * HH + 4 * k);
            #pragma unroll
            for (int d = 0; d < DD; ++d) {
                int e = sEdges[n * DD + d];
                if (e >= 0) {
                    float4 v = *(const float4*)(sX + e * HH + 4 * k);
                    m.x = fmaxf(m.x, v.x); m.y = fmaxf(m.y, v.y);
                    m.z = fmaxf(m.z, v.z); m.w = fmaxf(m.w, v.w);
                }
            }
        }
        *(float4*)(sA + n * HH + 4 * k) = m;
    }
    __syncthreads();   // sFeat/sX now dead -> sU becomes sWo

    // ---- Phase 4b: stage Wo into LDS once per block ----
    for (int idx = t; idx < IN2 * HH; idx += T) sWo[idx] = Wo[idx];
    __syncthreads();

    // ---- Phase 5: gout: per-wave tile of 8 nodes; partials of tanh ----
    {
        const int base = wv * 8;
        int nd[8], nr[8];
        #pragma unroll
        for (int j = 0; j < 8; ++j) {
            int n = base + j;
            bool ok = (n < NN) && (sDeg[n] > 0);
            nd[j] = ok ? n : -1;
            nr[j] = (n < NN) ? n : 0;
        }
        const float bb0 = bo[h0], bb1 = bo[h1];
        float a0[8], a1[8];
        #pragma unroll
        for (int j = 0; j < 8; ++j) { a0[j] = bb0; a1[j] = bb1; }
        for (int ic = 0; ic < HH; ic += 4) {
            float w0[4], w1[4];
            #pragma unroll
            for (int k = 0; k < 4; ++k) {
                w0[k] = sWo[(ic + k) * HH + h0];
                w1[k] = sWo[(ic + k) * HH + h1];
            }
            #pragma unroll
            for (int jh = 0; jh < 2; ++jh) {
                float4 f[4];
                #pragma unroll
                for (int j = 0; j < 4; ++j)
                    f[j] = *(const float4*)(sA + nr[jh * 4 + j] * HH + ic);
                #pragma unroll
                for (int j = 0; j < 4; ++j) {
                    const int jj = jh * 4 + j;
                    a0[jj] = fmaf(f[j].x, w0[0], a0[jj]);
                    a0[jj] = fmaf(f[j].y, w0[1], a0[jj]);
                    a0[jj] = fmaf(f[j].z, w0[2], a0[jj]);
                    a0[jj] = fmaf(f[j].w, w0[3], a0[jj]);
                    a1[jj] = fmaf(f[j].x, w1[0], a1[jj]);
                    a1[jj] = fmaf(f[j].y, w1[1], a1[jj]);
                    a1[jj] = fmaf(f[j].z, w1[2], a1[jj]);
                    a1[jj] = fmaf(f[j].w, w1[3], a1[jj]);
                }
            }
        }
        #pragma unroll
        for (int jb = 0; jb < BFD; ++jb) {
            const float w0v = sWo[(HH + jb) * HH + h0];
            const float w1v = sWo[(HH + jb) * HH + h1];
            #pragma unroll
            for (int j = 0; j < 8; ++j) {
                const float fv = sBsum[nr[j] * BFD + jb];
                a0[j] = fmaf(fv, w0v, a0[j]);
                a1[j] = fmaf(fv, w1v, a1[j]);
            }
        }
        float p0 = 0.f, p1 = 0.f;
        #pragma unroll
        for (int j = 0; j < 8; ++j) {
            if (nd[j] >= 0) { p0 += tanhf(a0[j]); p1 += tanhf(a1[j]); }
        }
        sPart[wv * HH + h0] = p0;
        sPart[wv * HH + h1] = p1;
    }
    __syncthreads();

    // ---- Phase 6: reduce 8 wave-partials, final FC + sigmoid ----
    if (t < HH) {
        float s = 0.f;
        #pragma unroll
        for (int w = 0; w < 8; ++w) s += sPart[w * HH + t];
        sPart[t] = s;
    }
    __syncthreads();
    if (t < CC) {
        float acc = bfc[t];
        #pragma unroll 16
        for (int i = 0; i < HH; ++i) acc = fmaf(sPart[i], Wfc[i * CC + t], acc);
        out[b * CC + t] = 1.f / (1.f + expf(-acc));
    }
}

extern "C" void kernel_launch(void* const* d_in, const int* in_sizes, int n_in,
                              void* d_out, int out_size, void* d_ws, size_t ws_size,
                              hipStream_t stream) {
    const float* atoms = (const float*)d_in[0];
    const float* bonds = (const float*)d_in[1];
    const int*   edges = (const int*)d_in[2];
    const float* W1  = (const float*)d_in[3];
    const float* b1  = (const float*)d_in[4];
    const float* W2  = (const float*)d_in[5];
    const float* b2  = (const float*)d_in[6];
    const float* Wo  = (const float*)d_in[7];
    const float* bo  = (const float*)d_in[8];
    const float* Wfc = (const float*)d_in[9];
    const float* bfc = (const float*)d_in[10];
    float* out = (float*)d_out;

    ngfp_kernel<<<NB, T, 0, stream>>>(atoms, bonds, edges, W1, b1, W2, b2,
                                      Wo, bo, Wfc, bfc, out);
}

// Round 4
// 513.047 us; speedup vs baseline: 1.6604x; 1.6604x over previous
//
#include <hip/hip_runtime.h>
#include <math.h>

// Shapes (fixed by reference setup_inputs)
constexpr int NB  = 2048;   // batch (graphs)
constexpr int NN  = 60;     // nodes per graph
constexpr int DD  = 6;      // max degree slots
constexpr int AF  = 37;     // atom features
constexpr int BFD = 6;      // bond features
constexpr int HH  = 128;    // hidden
constexpr int CC  = 12;     // classes
constexpr int IN1 = AF + BFD;   // 43
constexpr int IN2 = HH + BFD;   // 134
constexpr int IN1P = 44;        // padded stride (16B-aligned rows)
constexpr int IN2P = 136;
constexpr int T   = 512;        // threads per block (8 waves)
constexpr int MAXT = 16;        // degree-pure tiles of 8

// Degree-pure conv: each lane computes 8 nodes x 2 h-cols. One weight stream
// per tile reused 16x in registers. `#pragma unroll 2` on the k-loop: the
// full unroll (compile-time trip 10/33) hoisted all weight loads -> ~950 B
// of scratch spill per thread (R2/R3: 1 GB WRITE_SIZE). Capped unroll keeps
// live pressure ~60 VGPRs, no spill.
template<int IN, int INP>
__device__ __forceinline__ void conv_tiles(
    const float* __restrict__ W,     // (D,IN,H) global
    const float* __restrict__ bias,  // (D,H) global
    const float* sFeat,              // LDS, stride INP, 16B-aligned rows
    float* sOut,                     // LDS, stride HH
    const int* sTileNode, const int* sTileDeg, int nT,
    int wv, int lane)
{
    const int h0 = lane, h1 = lane + 64;
    for (int tile = wv; tile < nT; tile += 8) {
        const int dg = sTileDeg[tile];
        int nd[8], nr[8];
        #pragma unroll
        for (int j = 0; j < 8; ++j) nd[j] = sTileNode[tile * 8 + j];
        const int n0 = nd[0];
        #pragma unroll
        for (int j = 0; j < 8; ++j) nr[j] = (nd[j] >= 0) ? nd[j] : n0;
        const float* Wr = W + (size_t)dg * IN * HH;
        const float bb0 = bias[dg * HH + h0];
        const float bb1 = bias[dg * HH + h1];
        float a0[8], a1[8];
        #pragma unroll
        for (int j = 0; j < 8; ++j) { a0[j] = bb0; a1[j] = bb1; }

        constexpr int KM = IN & ~3;
        #pragma unroll 2
        for (int ic = 0; ic < KM; ic += 4) {
            float w0[4], w1[4];
            #pragma unroll
            for (int k = 0; k < 4; ++k) {
                w0[k] = Wr[(ic + k) * HH + h0];
                w1[k] = Wr[(ic + k) * HH + h1];
            }
            #pragma unroll
            for (int jh = 0; jh < 2; ++jh) {
                float4 f[4];
                #pragma unroll
                for (int j = 0; j < 4; ++j)
                    f[j] = *(const float4*)(sFeat + nr[jh * 4 + j] * INP + ic);
                #pragma unroll
                for (int j = 0; j < 4; ++j) {
                    const int jj = jh * 4 + j;
                    a0[jj] = fmaf(f[j].x, w0[0], a0[jj]);
                    a0[jj] = fmaf(f[j].y, w0[1], a0[jj]);
                    a0[jj] = fmaf(f[j].z, w0[2], a0[jj]);
                    a0[jj] = fmaf(f[j].w, w0[3], a0[jj]);
                    a1[jj] = fmaf(f[j].x, w1[0], a1[jj]);
                    a1[jj] = fmaf(f[j].y, w1[1], a1[jj]);
                    a1[jj] = fmaf(f[j].z, w1[2], a1[jj]);
                    a1[jj] = fmaf(f[j].w, w1[3], a1[jj]);
                }
            }
        }
        #pragma unroll 1
        for (int i = KM; i < IN; ++i) {   // remainder (3 for IN1, 2 for IN2)
            const float w0v = Wr[i * HH + h0];
            const float w1v = Wr[i * HH + h1];
            #pragma unroll
            for (int j = 0; j < 8; ++j) {
                const float fv = sFeat[nr[j] * INP + i];
                a0[j] = fmaf(fv, w0v, a0[j]);
                a1[j] = fmaf(fv, w1v, a1[j]);
            }
        }
        #pragma unroll
        for (int j = 0; j < 8; ++j) {
            if (nd[j] >= 0) {   // wave-uniform guard (skip duplicate pads)
                sOut[nd[j] * HH + h0] = fmaxf(a0[j], 0.f);
                sOut[nd[j] * HH + h1] = fmaxf(a1[j], 0.f);
            }
        }
    }
}

__global__ __launch_bounds__(T, 2) void ngfp_kernel(
    const float* __restrict__ atoms,  // (B,N,AF)
    const float* __restrict__ bonds,  // (B,N,D,BFD)
    const int*   __restrict__ edges,  // (B,N,D), -1 pad
    const float* __restrict__ W1,     // (D,IN1,H)
    const float* __restrict__ b1,     // (D,H)
    const float* __restrict__ W2,     // (D,IN2,H)
    const float* __restrict__ b2,     // (D,H)
    const float* __restrict__ Wo,     // (IN2,H)
    const float* __restrict__ bo,     // (H)
    const float* __restrict__ Wfc,    // (H,C)
    const float* __restrict__ bfc,    // (C)
    float* __restrict__ out)          // (B,C)
{
    __shared__ float sA[NN * HH];          // 30720 B
    __shared__ float sU[IN2 * HH];         // 68608 B (union region)
    __shared__ float sBsum[NN * BFD];
    __shared__ int   sEdges[NN * DD];
    __shared__ int   sDeg[NN];
    __shared__ int   sCnt[8];
    __shared__ int   sTStart[8];
    __shared__ int   sTileNode[MAXT * 8];
    __shared__ int   sTileDeg[MAXT];
    __shared__ int   sNumTiles;
    __shared__ float sPart[8 * HH];

    float* const sFeat = sU;
    float* const sX    = sU + NN * IN2P;
    float* const sWo   = sU;               // alias, used after conv phases

    const int b = blockIdx.x;
    const int t = threadIdx.x;
    const int wv = t >> 6;
    const int lane = t & 63;
    const int h0 = lane, h1 = lane + 64;

    // ---- Phase 0: stage edges, atoms, bond-sums ----
    for (int i = t; i < NN * DD; i += T) sEdges[i] = edges[b * NN * DD + i];
    for (int i = t; i < NN * AF; i += T) sA[i] = atoms[b * NN * AF + i];
    for (int i = t; i < NN * BFD; i += T) {
        int n = i / BFD, f = i - n * BFD;
        const float* bp = bonds + ((size_t)(b * NN + n) * DD) * BFD + f;
        float s = 0.f;
        #pragma unroll
        for (int d = 0; d < DD; ++d) s += bp[d * BFD];
        sBsum[i] = s;
    }
    __syncthreads();

    // ---- Phase 0b: degree + feat1 build ----
    if (t < NN) {
        int dg = 0;
        #pragma unroll
        for (int d = 0; d < DD; ++d) dg += (sEdges[t * DD + d] != -1) ? 1 : 0;
        sDeg[t] = dg;
    }
    for (int idx = t; idx < NN * IN1; idx += T) {
        int n = idx / IN1, i = idx - n * IN1;
        float v;
        if (i < AF) {
            v = sA[n * AF + i];
            #pragma unroll
            for (int d = 0; d < DD; ++d) {
                int e = sEdges[n * DD + d];
                if (e >= 0) v += sA[e * AF + i];
            }
        } else {
            v = sBsum[n * BFD + (i - AF)];
        }
        sFeat[n * IN1P + i] = v;
    }
    __syncthreads();

    // ---- Phase 0c: degree-pure tiles of 8 (counting sort, pad -1) ----
    if (t < 7) {
        int c = 0;
        for (int n = 0; n < NN; ++n) c += (sDeg[n] == t) ? 1 : 0;
        sCnt[t] = c;
    }
    __syncthreads();
    if (t == 0) {
        int nt = 0;
        for (int d = 0; d < 7; ++d) { sTStart[d] = nt; nt += (sCnt[d] + 7) / 8; }
        sNumTiles = nt;
    }
    __syncthreads();
    if (t < 7) {
        const int d = t;
        int tile = sTStart[d], c = 0;
        for (int n = 0; n < NN; ++n) {
            if (sDeg[n] == d) {
                sTileNode[tile * 8 + (c & 7)] = n;
                ++c;
                if ((c & 7) == 0) ++tile;
            }
        }
        if ((c & 7) != 0) {
            for (int j = (c & 7); j < 8; ++j) sTileNode[tile * 8 + j] = -1;
        }
        const int tend = sTStart[d] + (sCnt[d] + 7) / 8;
        for (int tt = sTStart[d]; tt < tend; ++tt) sTileDeg[tt] = d;
    }
    __syncthreads();
    const int nT = sNumTiles;

    // ---- Phase 1: conv1 -> sA ----
    conv_tiles<IN1, IN1P>(W1, b1, sFeat, sA, sTileNode, sTileDeg, nT, wv, lane);
    __syncthreads();

    // ---- Phase 2: pool1 -> sX ----
    for (int idx = t; idx < NN * (HH / 4); idx += T) {
        int n = idx >> 5, k = idx & 31;
        float4 m;
        if (sDeg[n] == 0) {
            m = make_float4(0.f, 0.f, 0.f, 0.f);
        } else {
            m = *(const float4*)(sA + n * HH + 4 * k);
            #pragma unroll
            for (int d = 0; d < DD; ++d) {
                int e = sEdges[n * DD + d];
                if (e >= 0) {
                    float4 v = *(const float4*)(sA + e * HH + 4 * k);
                    m.x = fmaxf(m.x, v.x); m.y = fmaxf(m.y, v.y);
                    m.z = fmaxf(m.z, v.z); m.w = fmaxf(m.w, v.w);
                }
            }
        }
        *(float4*)(sX + n * HH + 4 * k) = m;
    }
    __syncthreads();

    // ---- Phase 3a: feat2 = (self+nbr sums of X2 | bsum), stride IN2P ----
    for (int idx = t; idx < NN * (HH / 4); idx += T) {
        int n = idx >> 5, k = idx & 31;
        float4 v = *(const float4*)(sX + n * HH + 4 * k);
        #pragma unroll
        for (int d = 0; d < DD; ++d) {
            int e = sEdges[n * DD + d];
            if (e >= 0) {
                float4 u = *(const float4*)(sX + e * HH + 4 * k);
                v.x += u.x; v.y += u.y; v.z += u.z; v.w += u.w;
            }
        }
        *(float4*)(sFeat + n * IN2P + 4 * k) = v;
    }
    for (int idx = t; idx < NN * BFD; idx += T) {
        int n = idx / BFD, jb = idx - n * BFD;
        sFeat[n * IN2P + HH + jb] = sBsum[idx];
    }
    __syncthreads();

    // ---- Phase 3b: conv2 -> sX ----
    conv_tiles<IN2, IN2P>(W2, b2, sFeat, sX, sTileNode, sTileDeg, nT, wv, lane);
    __syncthreads();

    // ---- Phase 4: pool2 -> sA ----
    for (int idx = t; idx < NN * (HH / 4); idx += T) {
        int n = idx >> 5, k = idx & 31;
        float4 m;
        if (sDeg[n] == 0) {
            m = make_float4(0.f, 0.f, 0.f, 0.f);
        } else {
            m = *(const float4*)(sX + n * HH + 4 * k);
            #pragma unroll
            for (int d = 0; d < DD; ++d) {
                int e = sEdges[n * DD + d];
                if (e >= 0) {
                    float4 v = *(const float4*)(sX + e * HH + 4 * k);
                    m.x = fmaxf(m.x, v.x); m.y = fmaxf(m.y, v.y);
                    m.z = fmaxf(m.z, v.z); m.w = fmaxf(m.w, v.w);
                }
            }
        }
        *(float4*)(sA + n * HH + 4 * k) = m;
    }
    __syncthreads();   // sFeat/sX now dead -> sU becomes sWo

    // ---- Phase 4b: stage Wo into LDS once per block ----
    for (int idx = t; idx < IN2 * HH; idx += T) sWo[idx] = Wo[idx];
    __syncthreads();

    // ---- Phase 5: gout: per-wave tile of 8 nodes; partials of tanh ----
    {
        const int base = wv * 8;
        int nd[8], nr[8];
        #pragma unroll
        for (int j = 0; j < 8; ++j) {
            int n = base + j;
            bool ok = (n < NN) && (sDeg[n] > 0);
            nd[j] = ok ? n : -1;
            nr[j] = (n < NN) ? n : 0;
        }
        const float bb0 = bo[h0], bb1 = bo[h1];
        float a0[8], a1[8];
        #pragma unroll
        for (int j = 0; j < 8; ++j) { a0[j] = bb0; a1[j] = bb1; }
        #pragma unroll 2
        for (int ic = 0; ic < HH; ic += 4) {
            float w0[4], w1[4];
            #pragma unroll
            for (int k = 0; k < 4; ++k) {
                w0[k] = sWo[(ic + k) * HH + h0];
                w1[k] = sWo[(ic + k) * HH + h1];
            }
            #pragma unroll
            for (int jh = 0; jh < 2; ++jh) {
                float4 f[4];
                #pragma unroll
                for (int j = 0; j < 4; ++j)
                    f[j] = *(const float4*)(sA + nr[jh * 4 + j] * HH + ic);
                #pragma unroll
                for (int j = 0; j < 4; ++j) {
                    const int jj = jh * 4 + j;
                    a0[jj] = fmaf(f[j].x, w0[0], a0[jj]);
                    a0[jj] = fmaf(f[j].y, w0[1], a0[jj]);
                    a0[jj] = fmaf(f[j].z, w0[2], a0[jj]);
                    a0[jj] = fmaf(f[j].w, w0[3], a0[jj]);
                    a1[jj] = fmaf(f[j].x, w1[0], a1[jj]);
                    a1[jj] = fmaf(f[j].y, w1[1], a1[jj]);
                    a1[jj] = fmaf(f[j].z, w1[2], a1[jj]);
                    a1[jj] = fmaf(f[j].w, w1[3], a1[jj]);
                }
            }
        }
        #pragma unroll
        for (int jb = 0; jb < BFD; ++jb) {
            const float w0v = sWo[(HH + jb) * HH + h0];
            const float w1v = sWo[(HH + jb) * HH + h1];
            #pragma unroll
            for (int j = 0; j < 8; ++j) {
                const float fv = sBsum[nr[j] * BFD + jb];
                a0[j] = fmaf(fv, w0v, a0[j]);
                a1[j] = fmaf(fv, w1v, a1[j]);
            }
        }
        float p0 = 0.f, p1 = 0.f;
        #pragma unroll
        for (int j = 0; j < 8; ++j) {
            if (nd[j] >= 0) { p0 += tanhf(a0[j]); p1 += tanhf(a1[j]); }
        }
        sPart[wv * HH + h0] = p0;
        sPart[wv * HH + h1] = p1;
    }
    __syncthreads();

    // ---- Phase 6: reduce 8 wave-partials, final FC + sigmoid ----
    if (t < HH) {
        float s = 0.f;
        #pragma unroll
        for (int w = 0; w < 8; ++w) s += sPart[w * HH + t];
        sPart[t] = s;
    }
    __syncthreads();
    if (t < CC) {
        float acc = bfc[t];
        #pragma unroll 16
        for (int i = 0; i < HH; ++i) acc = fmaf(sPart[i], Wfc[i * CC + t], acc);
        out[b * CC + t] = 1.f / (1.f + expf(-acc));
    }
}

extern "C" void kernel_launch(void* const* d_in, const int* in_sizes, int n_in,
                              void* d_out, int out_size, void* d_ws, size_t ws_size,
                              hipStream_t stream) {
    const float* atoms = (const float*)d_in[0];
    const float* bonds = (const float*)d_in[1];
    const int*   edges = (const int*)d_in[2];
    const float* W1  = (const float*)d_in[3];
    const float* b1  = (const float*)d_in[4];
    const float* W2  = (const float*)d_in[5];
    const float* b2  = (const float*)d_in[6];
    const float* Wo  = (const float*)d_in[7];
    const float* bo  = (const float*)d_in[8];
    const float* Wfc = (const float*)d_in[9];
    const float* bfc = (const float*)d_in[10];
    float* out = (float*)d_out;

    ngfp_kernel<<<NB, T, 0, stream>>>(atoms, bonds, edges, W1, b1, W2, b2,
                                      Wo, bo, Wfc, bfc, out);
}

// Round 6
// 377.196 us; speedup vs baseline: 2.2585x; 1.3602x over previous
//
#include <hip/hip_runtime.h>
#include <math.h>

typedef unsigned short u16;
typedef unsigned int   u32;
typedef short  v8s __attribute__((ext_vector_type(8)));   // 8 bf16 = 4 VGPRs (MFMA A/B frag)
typedef float  v4f __attribute__((ext_vector_type(4)));   // MFMA C/D frag

constexpr int NB=2048, NN=60, DD=6, AF=37, BFD=6, HH=128, CC=12;
constexpr int T = 512;          // 8 waves
constexpr int FASTR = 168;      // A-buffer row stride (bf16); rows 0..63 = hi, 64..127 = lo
constexpr int KS1 = 2;          // conv1: K=43 -> 64  (2 k-steps of 32)
constexpr int KS2 = 5;          // conv2/gout: K=134 -> 160 (5 k-steps)

// d_ws layout: 1KB fragment blocks per (d, ntile, kstep); hi table first, then the
// lo (residual) mirror at LO_OFF. Lane l owns bytes l*16..+15 of each block.
constexpr int W1T_UNITS = 6*8*KS1;   // 96
constexpr int W2T_UNITS = 6*8*KS2;   // 240
constexpr int WOT_UNITS = 8*KS2;     // 40
constexpr int TOT_UNITS = W1T_UNITS + W2T_UNITS + WOT_UNITS;   // 376 blocks x2 = 770 KB
constexpr int W2T_OFF = W1T_UNITS*512;                 // in u16 elements
constexpr int WOT_OFF = (W1T_UNITS+W2T_UNITS)*512;
constexpr int LO_OFF  = TOT_UNITS*512;                 // lo mirror offset (u16 elements)

__device__ __forceinline__ u16 f2bf(float f) {         // RNE fp32->bf16 (finite inputs)
  u32 u = __float_as_uint(f);
  return (u16)((u + 0x7FFFu + ((u >> 16) & 1u)) >> 16);
}
__device__ __forceinline__ float bf2f(u16 h) { return __uint_as_float((u32)h << 16); }
// split pair (a,b) -> packed hi bf16x2 and lo (residual) bf16x2
__device__ __forceinline__ void split2(float a, float b, u32& hi, u32& lo) {
  u16 ha = f2bf(a), hb = f2bf(b);
  u16 la = f2bf(a - bf2f(ha)), lb = f2bf(b - bf2f(hb));
  hi = ((u32)hb << 16) | ha;
  lo = ((u32)lb << 16) | la;
}
__device__ __forceinline__ void split8(const float* v, uint4& hi, uint4& lo) {
  split2(v[0], v[1], hi.x, lo.x); split2(v[2], v[3], hi.y, lo.y);
  split2(v[4], v[5], hi.z, lo.z); split2(v[6], v[7], hi.w, lo.w);
}

// ---- prep: swizzle W1/W2/Wo (fp32, k-major) into bf16 hi/lo MFMA B-frag blocks ----
// B-frag for 16x16x32: lane l holds B[k = ks*32 + (l>>4)*8 + j][n = ntile*16 + (l&15)]
__global__ __launch_bounds__(256) void prep_kernel(
    const float* __restrict__ W1, const float* __restrict__ W2,
    const float* __restrict__ Wo, u16* __restrict__ ws)
{
  int tid = blockIdx.x*256 + threadIdx.x;
  if (tid >= TOT_UNITS*512) return;
  int unit = tid >> 9, idx = tid & 511;
  int lane = idx >> 3, j = idx & 7;
  int n16 = lane & 15, q = lane >> 4;
  const float* src; int K, nt, ks;
  if (unit < W1T_UNITS) {
    int d = unit / 16, rem = unit % 16; nt = rem >> 1; ks = rem & 1;
    src = W1 + (size_t)d*43*128; K = 43;
  } else if (unit < W1T_UNITS + W2T_UNITS) {
    int u = unit - W1T_UNITS; int d = u / 40, rem = u % 40; nt = rem / 5; ks = rem % 5;
    src = W2 + (size_t)d*134*128; K = 134;
  } else {
    int u = unit - (W1T_UNITS + W2T_UNITS); nt = u / 5; ks = u % 5;
    src = Wo; K = 134;
  }
  int k = ks*32 + q*8 + j, n = nt*16 + n16;
  float v = (k < K) ? src[(size_t)k*128 + n] : 0.f;
  u16 hi = f2bf(v);
  u16 lo = f2bf(v - bf2f(hi));
  ws[(size_t)unit*512 + lane*8 + j] = hi;
  ws[(size_t)(LO_OFF + unit*512) + lane*8 + j] = lo;
}

// ---- degree-ranged conv via bf16x3 MFMA: rows sorted by degree ----
template<int KSTEPS>
__device__ __forceinline__ void conv_mfma(
    const u16* __restrict__ wsW,      // hi table base for this weight (lo at +LO_OFF)
    const float* __restrict__ bias,   // (6,128) fp32 global
    const u16* sFA, float* sXout,     // LDS: A hi/lo tiles (sorted rows), X out fp32
    const int* sSorted, const int* sDeg, const int* sRowStart,
    int wv, int lane)
{
  const int n16 = lane & 15, q = lane >> 4;
  for (int d = 0; d < 7; ++d) {
    const int rs = sRowStart[d], re = sRowStart[d+1];
    if (rs == re) continue;
    const int mt0 = rs >> 4, mt1 = (re + 15) >> 4;
    const int units = (mt1 - mt0) * 8;
    if (d == 6) {                    // ref zeroes deg-6 (W has rows 0..5); not hit in practice
      for (int u = wv; u < units; u += 8) {
        int mt = mt0 + (u >> 3), nt = u & 7, h = nt*16 + n16;
        #pragma unroll
        for (int r = 0; r < 4; ++r) {
          int node = sSorted[mt*16 + q*4 + r];
          if (node >= 0 && sDeg[node] == 6) sXout[node*128 + h] = 0.f;
        }
      }
      continue;
    }
    for (int u = wv; u < units; u += 8) {
      const int mt = mt0 + (u >> 3), nt = u & 7;
      v4f acc = {0.f, 0.f, 0.f, 0.f};
      #pragma unroll
      for (int ks = 0; ks < KSTEPS; ++ks) {
        const int row = mt*16 + n16;
        v8s ah = *(const v8s*)(&sFA[row*FASTR + ks*32 + q*8]);
        v8s al = *(const v8s*)(&sFA[(64 + row)*FASTR + ks*32 + q*8]);
        const size_t ub = ((size_t)((d*8 + nt)*KSTEPS + ks))*512;
        v8s bh = ((const v8s*)(wsW + ub))[lane];
        v8s bl = ((const v8s*)(wsW + LO_OFF + ub))[lane];
        acc = __builtin_amdgcn_mfma_f32_16x16x32_bf16(ah, bh, acc, 0, 0, 0);
        acc = __builtin_amdgcn_mfma_f32_16x16x32_bf16(al, bh, acc, 0, 0, 0);
        acc = __builtin_amdgcn_mfma_f32_16x16x32_bf16(ah, bl, acc, 0, 0, 0);
      }
      const int h = nt*16 + n16;
      const float bb = bias[d*128 + h];
      #pragma unroll
      for (int r = 0; r < 4; ++r) {
        int node = sSorted[mt*16 + q*4 + r];
        if (node >= 0 && sDeg[node] == d)
          sXout[node*128 + h] = fmaxf(acc[r] + bb, 0.f);
      }
    }
  }
}

__global__ __launch_bounds__(T) void ngfp_kernel(
    const float* __restrict__ atoms, const float* __restrict__ bonds,
    const int*   __restrict__ edges,
    const float* __restrict__ b1, const float* __restrict__ b2,
    const float* __restrict__ bo,
    const float* __restrict__ Wfc, const float* __restrict__ bfc,
    const u16*   __restrict__ ws,
    float* __restrict__ out)
{
  __shared__ u16   sFA[128*FASTR];   // 43008 B — A-tiles hi (rows 0..63) + lo (64..127)
  __shared__ float sXa[NN*HH];       // 30720 B — X1 / x3 (fp32); aliases staged atoms
  __shared__ float sXb[NN*HH];       // 30720 B — X2 / x4 (fp32)
  __shared__ float sBsum[NN*BFD];
  __shared__ int  sEdges[NN*DD];
  __shared__ int  sDeg[NN];
  __shared__ int  sSorted[64];
  __shared__ int  sRowStart[8];
  __shared__ int  sCnt[8];
  __shared__ float sPart[HH];

  float* const sAtoms = sXa;   // 8880 B, dead once A1 built (conv1 then overwrites)

  const int b = blockIdx.x;
  const int t = threadIdx.x;
  const int wv = t >> 6;
  const int lane = t & 63;

  // ---- P0: stage edges, atoms, bond-sums; degree; counting sort by degree ----
  for (int i = t; i < NN*DD; i += T) sEdges[i] = edges[b*NN*DD + i];
  for (int i = t; i < NN*AF; i += T) sAtoms[i] = atoms[b*NN*AF + i];
  for (int i = t; i < NN*BFD; i += T) {
    int n = i / BFD, f = i - n*BFD;
    const float* bp = bonds + ((size_t)(b*NN + n)*DD)*BFD + f;
    float s = 0.f;
    #pragma unroll
    for (int d = 0; d < DD; ++d) s += bp[d*BFD];
    sBsum[i] = s;
  }
  __syncthreads();
  if (t < NN) {
    int dg = 0;
    #pragma unroll
    for (int d = 0; d < DD; ++d) dg += (sEdges[t*DD + d] != -1) ? 1 : 0;
    sDeg[t] = dg;
  }
  __syncthreads();
  if (t < 7) {
    int c = 0;
    for (int n = 0; n < NN; ++n) c += (sDeg[n] == t) ? 1 : 0;
    sCnt[t] = c;
  }
  __syncthreads();
  if (t == 0) {
    int rs = 0;
    for (int d = 0; d < 7; ++d) { sRowStart[d] = rs; rs += sCnt[d]; }
    sRowStart[7] = rs;   // == 60
  }
  __syncthreads();
  if (t < 7) {
    int idx = sRowStart[t];
    for (int n = 0; n < NN; ++n) if (sDeg[n] == t) sSorted[idx++] = n;
  }
  if (t == 0) { sSorted[60] = sSorted[61] = sSorted[62] = sSorted[63] = -1; }
  __syncthreads();

  // ---- P1: A1 build — feat1 (self+nbr atoms | bsum | 0-pad), sorted rows, hi/lo ----
  for (int unit = t; unit < 64*8; unit += T) {      // 8 chunks of 8 k (K padded to 64)
    int row = unit >> 3, c = unit & 7;
    int node = sSorted[row];
    float acc[8] = {0,0,0,0,0,0,0,0};
    if (node >= 0) {
      int e[DD];
      #pragma unroll
      for (int d = 0; d < DD; ++d) e[d] = sEdges[node*DD + d];
      #pragma unroll
      for (int j = 0; j < 8; ++j) {
        int k = c*8 + j;
        float v = 0.f;
        if (k < AF) {
          v = sAtoms[node*AF + k];
          #pragma unroll
          for (int d = 0; d < DD; ++d) if (e[d] >= 0) v += sAtoms[e[d]*AF + k];
        } else if (k < AF + BFD) {
          v = sBsum[node*BFD + (k - AF)];
        }
        acc[j] = v;
      }
    }
    uint4 hi, lo; split8(acc, hi, lo);
    *(uint4*)(&sFA[row*FASTR + c*8]) = hi;
    *(uint4*)(&sFA[(64 + row)*FASTR + c*8]) = lo;
  }
  __syncthreads();

  // ---- P2: conv1 MFMA -> X1 (sXa fp32) ----
  conv_mfma<KS1>(ws, b1, sFA, sXa, sSorted, sDeg, sRowStart, wv, lane);
  __syncthreads();

  // ---- P3: pool1: X2 = max(self, nbrs)(X1) * (deg>0) -> sXb (fp32) ----
  for (int idx = t; idx < NN*32; idx += T) {
    int n = idx >> 5, c = idx & 31;
    float4 m = {0.f, 0.f, 0.f, 0.f};
    if (sDeg[n] > 0) {
      m = *(const float4*)(&sXa[n*128 + c*4]);
      #pragma unroll
      for (int d = 0; d < DD; ++d) {
        int e = sEdges[n*DD + d];
        if (e >= 0) {
          float4 v = *(const float4*)(&sXa[e*128 + c*4]);
          m.x = fmaxf(m.x, v.x); m.y = fmaxf(m.y, v.y);
          m.z = fmaxf(m.z, v.z); m.w = fmaxf(m.w, v.w);
        }
      }
    }
    *(float4*)(&sXb[n*128 + c*4]) = m;
  }
  __syncthreads();

  // ---- P4: A2 build — feat2 = (self+nbr sums of X2 | bsum | pad), hi/lo ----
  for (int unit = t; unit < 64*16; unit += T) {
    int row = unit >> 4, c = unit & 15;
    int node = sSorted[row];
    float acc[8] = {0,0,0,0,0,0,0,0};
    if (node >= 0) {
      *(float4*)(&acc[0]) = *(const float4*)(&sXb[node*128 + c*8]);
      *(float4*)(&acc[4]) = *(const float4*)(&sXb[node*128 + c*8 + 4]);
      #pragma unroll
      for (int d = 0; d < DD; ++d) {
        int e = sEdges[node*DD + d];
        if (e >= 0) {
          float4 u0 = *(const float4*)(&sXb[e*128 + c*8]);
          float4 u1 = *(const float4*)(&sXb[e*128 + c*8 + 4]);
          acc[0]+=u0.x; acc[1]+=u0.y; acc[2]+=u0.z; acc[3]+=u0.w;
          acc[4]+=u1.x; acc[5]+=u1.y; acc[6]+=u1.z; acc[7]+=u1.w;
        }
      }
    }
    uint4 hi, lo; split8(acc, hi, lo);
    *(uint4*)(&sFA[row*FASTR + c*8]) = hi;
    *(uint4*)(&sFA[(64 + row)*FASTR + c*8]) = lo;
  }
  for (int idx = t; idx < 64*32; idx += T) {        // k = 128..159 tail (bsum | zeros)
    int row = idx >> 5, kk = idx & 31;
    int node = sSorted[row];
    float v = (node >= 0 && kk < BFD) ? sBsum[node*BFD + kk] : 0.f;
    u16 hi = f2bf(v);
    sFA[row*FASTR + 128 + kk] = hi;
    sFA[(64 + row)*FASTR + 128 + kk] = f2bf(v - bf2f(hi));
  }
  __syncthreads();

  // ---- P5: conv2 MFMA -> x3 (sXa) ----
  conv_mfma<KS2>(ws + W2T_OFF, b2, sFA, sXa, sSorted, sDeg, sRowStart, wv, lane);
  __syncthreads();

  // ---- P6: pool2: x4 = max(self, nbrs)(x3) -> sXb ----
  for (int idx = t; idx < NN*32; idx += T) {
    int n = idx >> 5, c = idx & 31;
    float4 m = {0.f, 0.f, 0.f, 0.f};
    if (sDeg[n] > 0) {
      m = *(const float4*)(&sXa[n*128 + c*4]);
      #pragma unroll
      for (int d = 0; d < DD; ++d) {
        int e = sEdges[n*DD + d];
        if (e >= 0) {
          float4 v = *(const float4*)(&sXa[e*128 + c*4]);
          m.x = fmaxf(m.x, v.x); m.y = fmaxf(m.y, v.y);
          m.z = fmaxf(m.z, v.z); m.w = fmaxf(m.w, v.w);
        }
      }
    }
    *(float4*)(&sXb[n*128 + c*4]) = m;
  }
  __syncthreads();

  // ---- P7: A3 build — gout features (x4 | bsum | pad), hi/lo ----
  for (int unit = t; unit < 64*16; unit += T) {
    int row = unit >> 4, c = unit & 15;
    int node = sSorted[row];
    float acc[8] = {0,0,0,0,0,0,0,0};
    if (node >= 0) {
      *(float4*)(&acc[0]) = *(const float4*)(&sXb[node*128 + c*8]);
      *(float4*)(&acc[4]) = *(const float4*)(&sXb[node*128 + c*8 + 4]);
    }
    uint4 hi, lo; split8(acc, hi, lo);
    *(uint4*)(&sFA[row*FASTR + c*8]) = hi;
    *(uint4*)(&sFA[(64 + row)*FASTR + c*8]) = lo;
  }
  for (int idx = t; idx < 64*32; idx += T) {
    int row = idx >> 5, kk = idx & 31;
    int node = sSorted[row];
    float v = (node >= 0 && kk < BFD) ? sBsum[node*BFD + kk] : 0.f;
    u16 hi = f2bf(v);
    sFA[row*FASTR + 128 + kk] = hi;
    sFA[(64 + row)*FASTR + 128 + kk] = f2bf(v - bf2f(hi));
  }
  __syncthreads();

  // ---- P8: gout MFMA: wave wv <-> n-tile wv; fp[h] = sum_n tanh(feat@Wo + bo) ----
  {
    const int nt = wv, n16 = lane & 15, q = lane >> 4;
    const int h = nt*16 + n16;
    const float bb = bo[h];
    float part = 0.f;
    for (int mt = 0; mt < 4; ++mt) {
      v4f acc = {0.f, 0.f, 0.f, 0.f};
      #pragma unroll
      for (int ks = 0; ks < KS2; ++ks) {
        const int row = mt*16 + n16;
        v8s ah = *(const v8s*)(&sFA[row*FASTR + ks*32 + q*8]);
        v8s al = *(const v8s*)(&sFA[(64 + row)*FASTR + ks*32 + q*8]);
        const size_t ub = WOT_OFF + ((size_t)(nt*KS2 + ks))*512;
        v8s bh = ((const v8s*)(ws + ub))[lane];
        v8s bl = ((const v8s*)(ws + LO_OFF + ub))[lane];
        acc = __builtin_amdgcn_mfma_f32_16x16x32_bf16(ah, bh, acc, 0, 0, 0);
        acc = __builtin_amdgcn_mfma_f32_16x16x32_bf16(al, bh, acc, 0, 0, 0);
        acc = __builtin_amdgcn_mfma_f32_16x16x32_bf16(ah, bl, acc, 0, 0, 0);
      }
      #pragma unroll
      for (int r = 0; r < 4; ++r) {
        int node = sSorted[mt*16 + q*4 + r];
        if (node >= 0 && sDeg[node] > 0) part += tanhf(acc[r] + bb);
      }
    }
    part += __shfl_xor(part, 16);
    part += __shfl_xor(part, 32);
    if (lane < 16) sPart[h] = part;
  }
  __syncthreads();

  // ---- P9: final FC + sigmoid ----
  if (t < CC) {
    float acc = bfc[t];
    #pragma unroll 16
    for (int i = 0; i < HH; ++i) acc = fmaf(sPart[i], Wfc[i*CC + t], acc);
    out[b*CC + t] = 1.f / (1.f + expf(-acc));
  }
}

extern "C" void kernel_launch(void* const* d_in, const int* in_sizes, int n_in,
                              void* d_out, int out_size, void* d_ws, size_t ws_size,
                              hipStream_t stream) {
  const float* atoms = (const float*)d_in[0];
  const float* bonds = (const float*)d_in[1];
  const int*   edges = (const int*)d_in[2];
  const float* W1  = (const float*)d_in[3];
  const float* b1  = (const float*)d_in[4];
  const float* W2  = (const float*)d_in[5];
  const float* b2  = (const float*)d_in[6];
  const float* Wo  = (const float*)d_in[7];
  const float* bo  = (const float*)d_in[8];
  const float* Wfc = (const float*)d_in[9];
  const float* bfc = (const float*)d_in[10];
  float* out = (float*)d_out;
  u16* ws = (u16*)d_ws;

  prep_kernel<<<(TOT_UNITS*512 + 255)/256, 256, 0, stream>>>(W1, W2, Wo, ws);
  ngfp_kernel<<<NB, T, 0, stream>>>(atoms, bonds, edges, b1, b2, bo, Wfc, bfc, ws, out);
}

// Round 7
// 261.856 us; speedup vs baseline: 3.2533x; 1.4405x over previous
//
#include <hip/hip_runtime.h>
#include <math.h>

typedef unsigned short u16;
typedef unsigned int   u32;
typedef short  v8s __attribute__((ext_vector_type(8)));   // 8 bf16 = 4 VGPRs (MFMA A/B frag)
typedef float  v4f __attribute__((ext_vector_type(4)));   // MFMA C/D frag

constexpr int NB=2048, NN=60, DD=6, AF=37, BFD=6, HH=128, CC=12;
constexpr int T = 512;          // 8 waves
constexpr int FASTR = 168;      // A-buffer row stride (bf16); rows 0..63 = hi, 64..127 = lo
constexpr int XSTR  = 132;      // X-buffer row stride (fp32): 528 B, breaks pow2 bank alias
constexpr int KS1 = 2;          // conv1: K=43 -> 64  (2 k-steps of 32)
constexpr int KS2 = 5;          // conv2/gout: K=134 -> 160 (5 k-steps)
constexpr int MAXP = 32;        // (degree, mtile) pair list bound

// d_ws layout: 1KB fragment blocks per (d, ntile, kstep); hi table, lo mirror at LO_OFF.
constexpr int W1T_UNITS = 6*8*KS1;   // 96
constexpr int W2T_UNITS = 6*8*KS2;   // 240
constexpr int WOT_UNITS = 8*KS2;     // 40
constexpr int TOT_UNITS = W1T_UNITS + W2T_UNITS + WOT_UNITS;   // 376 x2 = 770 KB
constexpr int W2T_OFF = W1T_UNITS*512;
constexpr int WOT_OFF = (W1T_UNITS+W2T_UNITS)*512;
constexpr int LO_OFF  = TOT_UNITS*512;

__device__ __forceinline__ u16 f2bf(float f) {         // RNE fp32->bf16 (finite inputs)
  u32 u = __float_as_uint(f);
  return (u16)((u + 0x7FFFu + ((u >> 16) & 1u)) >> 16);
}
__device__ __forceinline__ float bf2f(u16 h) { return __uint_as_float((u32)h << 16); }
__device__ __forceinline__ void split2(float a, float b, u32& hi, u32& lo) {
  u16 ha = f2bf(a), hb = f2bf(b);
  u16 la = f2bf(a - bf2f(ha)), lb = f2bf(b - bf2f(hb));
  hi = ((u32)hb << 16) | ha;
  lo = ((u32)lb << 16) | la;
}
__device__ __forceinline__ void split8(const float* v, uint4& hi, uint4& lo) {
  split2(v[0], v[1], hi.x, lo.x); split2(v[2], v[3], hi.y, lo.y);
  split2(v[4], v[5], hi.z, lo.z); split2(v[6], v[7], hi.w, lo.w);
}

// ---- prep: swizzle W1/W2/Wo (fp32, k-major) into bf16 hi/lo MFMA B-frag blocks ----
// B-frag for 16x16x32: lane l holds B[k = ks*32 + (l>>4)*8 + j][n = ntile*16 + (l&15)]
__global__ __launch_bounds__(256) void prep_kernel(
    const float* __restrict__ W1, const float* __restrict__ W2,
    const float* __restrict__ Wo, u16* __restrict__ ws)
{
  int tid = blockIdx.x*256 + threadIdx.x;
  if (tid >= TOT_UNITS*512) return;
  int unit = tid >> 9, idx = tid & 511;
  int lane = idx >> 3, j = idx & 7;
  int n16 = lane & 15, q = lane >> 4;
  const float* src; int K, nt, ks;
  if (unit < W1T_UNITS) {
    int d = unit / 16, rem = unit % 16; nt = rem >> 1; ks = rem & 1;
    src = W1 + (size_t)d*43*128; K = 43;
  } else if (unit < W1T_UNITS + W2T_UNITS) {
    int u = unit - W1T_UNITS; int d = u / 40, rem = u % 40; nt = rem / 5; ks = rem % 5;
    src = W2 + (size_t)d*134*128; K = 134;
  } else {
    int u = unit - (W1T_UNITS + W2T_UNITS); nt = u / 5; ks = u % 5;
    src = Wo; K = 134;
  }
  int k = ks*32 + q*8 + j, n = nt*16 + n16;
  float v = (k < K) ? src[(size_t)k*128 + n] : 0.f;
  u16 hi = f2bf(v);
  u16 lo = f2bf(v - bf2f(hi));
  ws[(size_t)unit*512 + lane*8 + j] = hi;
  ws[(size_t)(LO_OFF + unit*512) + lane*8 + j] = lo;
}

// ---- conv via bf16x3 MFMA: wave owns a (degree, mtile) pair, A hi/lo hoisted to
// regs (reused across all 8 ntiles -> 8x fewer ds_read_b128 than per-ntile reads) ----
template<int KSTEPS>
__device__ __forceinline__ void conv_mfma(
    const u16* __restrict__ wsW, const float* __restrict__ bias,
    const u16* sFA, float* sXout,
    const int* sSorted, const int* sDeg,
    const int* sPairD, const int* sPairM, int nP,
    int wv, int lane)
{
  const int n16 = lane & 15, q = lane >> 4;
  for (int p = wv; p < nP; p += 8) {
    const int d = sPairD[p], mt = sPairM[p];
    const int row = mt*16 + n16;
    int nodes[4];
    #pragma unroll
    for (int r = 0; r < 4; ++r) nodes[r] = sSorted[mt*16 + q*4 + r];
    if (d == 6) {                    // ref zeroes deg-6 (W rows 0..5); not hit in practice
      #pragma unroll 1
      for (int nt = 0; nt < 8; ++nt) {
        const int h = nt*16 + n16;
        #pragma unroll
        for (int r = 0; r < 4; ++r)
          if (nodes[r] >= 0 && sDeg[nodes[r]] == 6) sXout[nodes[r]*XSTR + h] = 0.f;
      }
      continue;
    }
    v8s ah[KSTEPS], al[KSTEPS];
    #pragma unroll
    for (int ks = 0; ks < KSTEPS; ++ks) {
      ah[ks] = *(const v8s*)(&sFA[row*FASTR + ks*32 + q*8]);
      al[ks] = *(const v8s*)(&sFA[(64 + row)*FASTR + ks*32 + q*8]);
    }
    #pragma unroll 2
    for (int nt = 0; nt < 8; ++nt) {
      v4f acc = {0.f, 0.f, 0.f, 0.f};
      #pragma unroll
      for (int ks = 0; ks < KSTEPS; ++ks) {
        const size_t ub = ((size_t)((d*8 + nt)*KSTEPS + ks))*512;
        v8s bh = ((const v8s*)(wsW + ub))[lane];
        v8s bl = ((const v8s*)(wsW + LO_OFF + ub))[lane];
        acc = __builtin_amdgcn_mfma_f32_16x16x32_bf16(ah[ks], bh, acc, 0, 0, 0);
        acc = __builtin_amdgcn_mfma_f32_16x16x32_bf16(al[ks], bh, acc, 0, 0, 0);
        acc = __builtin_amdgcn_mfma_f32_16x16x32_bf16(ah[ks], bl, acc, 0, 0, 0);
      }
      const int h = nt*16 + n16;
      const float bb = bias[d*128 + h];
      #pragma unroll
      for (int r = 0; r < 4; ++r) {
        int node = nodes[r];
        if (node >= 0 && sDeg[node] == d)
          sXout[node*XSTR + h] = fmaxf(acc[r] + bb, 0.f);
      }
    }
  }
}

__global__ __launch_bounds__(T) void ngfp_kernel(
    const float* __restrict__ atoms, const float* __restrict__ bonds,
    const int*   __restrict__ edges,
    const float* __restrict__ b1, const float* __restrict__ b2,
    const float* __restrict__ bo,
    const float* __restrict__ Wfc, const float* __restrict__ bfc,
    const u16*   __restrict__ ws,
    float* __restrict__ out)
{
  __shared__ u16   sFA[128*FASTR];   // 43008 B — A-tiles hi (rows 0..63) + lo (64..127)
  __shared__ float sXa[NN*XSTR];     // 31680 B — X1/X2/x3/x4 (fp32, in-place pools)
  __shared__ float sBsum[NN*BFD];
  __shared__ int  sEdges[NN*DD];
  __shared__ int  sDeg[NN];
  __shared__ int  sSorted[64];
  __shared__ int  sRowStart[8];
  __shared__ int  sCnt[8];
  __shared__ int  sPairD[MAXP];
  __shared__ int  sPairM[MAXP];
  __shared__ int  sNP;
  __shared__ float sPart[HH];
  // total ~78.9 KB -> 2 blocks/CU (160 KB LDS), 16 waves/CU

  float* const sAtoms = sXa;   // compact (n*AF+i) staging, dead once A1 built

  const int b = blockIdx.x;
  const int t = threadIdx.x;
  const int wv = t >> 6;
  const int lane = t & 63;

  // ---- P0: stage edges, atoms, bond-sums; degree; counting sort; pair list ----
  for (int i = t; i < NN*DD; i += T) sEdges[i] = edges[b*NN*DD + i];
  for (int i = t; i < NN*AF; i += T) sAtoms[i] = atoms[b*NN*AF + i];
  for (int i = t; i < NN*BFD; i += T) {
    int n = i / BFD, f = i - n*BFD;
    const float* bp = bonds + ((size_t)(b*NN + n)*DD)*BFD + f;
    float s = 0.f;
    #pragma unroll
    for (int d = 0; d < DD; ++d) s += bp[d*BFD];
    sBsum[i] = s;
  }
  __syncthreads();
  if (t < NN) {
    int dg = 0;
    #pragma unroll
    for (int d = 0; d < DD; ++d) dg += (sEdges[t*DD + d] != -1) ? 1 : 0;
    sDeg[t] = dg;
  }
  __syncthreads();
  if (t < 7) {
    int c = 0;
    for (int n = 0; n < NN; ++n) c += (sDeg[n] == t) ? 1 : 0;
    sCnt[t] = c;
  }
  __syncthreads();
  if (t == 0) {
    int rs = 0;
    for (int d = 0; d < 7; ++d) { sRowStart[d] = rs; rs += sCnt[d]; }
    sRowStart[7] = rs;   // == 60
    int np = 0;
    for (int d = 0; d < 7; ++d) {
      int r0 = sRowStart[d], r1 = sRowStart[d+1];
      if (r0 == r1) continue;
      for (int mt = r0 >> 4; mt < ((r1 + 15) >> 4); ++mt) {
        sPairD[np] = d; sPairM[np] = mt; ++np;
      }
    }
    sNP = np;
  }
  __syncthreads();
  if (t < 7) {
    int idx = sRowStart[t];
    for (int n = 0; n < NN; ++n) if (sDeg[n] == t) sSorted[idx++] = n;
  }
  if (t == 0) { sSorted[60] = sSorted[61] = sSorted[62] = sSorted[63] = -1; }
  __syncthreads();
  const int nP = sNP;

  // ---- P1: A1 build — feat1 (self+nbr atoms | bsum | 0-pad), sorted rows, hi/lo ----
  for (int unit = t; unit < 64*8; unit += T) {      // 8 chunks of 8 k (K padded to 64)
    int row = unit >> 3, c = unit & 7;
    int node = sSorted[row];
    float acc[8] = {0,0,0,0,0,0,0,0};
    if (node >= 0) {
      int e[DD];
      #pragma unroll
      for (int d = 0; d < DD; ++d) e[d] = sEdges[node*DD + d];
      #pragma unroll
      for (int j = 0; j < 8; ++j) {
        int k = c*8 + j;
        float v = 0.f;
        if (k < AF) {
          v = sAtoms[node*AF + k];
          #pragma unroll
          for (int d = 0; d < DD; ++d) if (e[d] >= 0) v += sAtoms[e[d]*AF + k];
        } else if (k < AF + BFD) {
          v = sBsum[node*BFD + (k - AF)];
        }
        acc[j] = v;
      }
    }
    uint4 hi, lo; split8(acc, hi, lo);
    *(uint4*)(&sFA[row*FASTR + c*8]) = hi;
    *(uint4*)(&sFA[(64 + row)*FASTR + c*8]) = lo;
  }
  __syncthreads();

  // ---- P2: conv1 MFMA -> X1 (sXa fp32) ----
  conv_mfma<KS1>(ws, b1, sFA, sXa, sSorted, sDeg, sPairD, sPairM, nP, wv, lane);
  __syncthreads();

  // ---- P3: pool1 IN PLACE: X2 = max(self, nbrs)(X1) * (deg>0) ----
  {
    float4 m[4];
    #pragma unroll
    for (int j = 0; j < 4; ++j) {
      int idx = t + j*T;
      if (idx < NN*32) {
        int n = idx >> 5, c = idx & 31;
        float4 v = {0.f, 0.f, 0.f, 0.f};
        if (sDeg[n] > 0) {
          v = *(const float4*)(&sXa[n*XSTR + c*4]);
          #pragma unroll
          for (int d = 0; d < DD; ++d) {
            int e = sEdges[n*DD + d];
            if (e >= 0) {
              float4 u = *(const float4*)(&sXa[e*XSTR + c*4]);
              v.x = fmaxf(v.x, u.x); v.y = fmaxf(v.y, u.y);
              v.z = fmaxf(v.z, u.z); v.w = fmaxf(v.w, u.w);
            }
          }
        }
        m[j] = v;
      }
    }
    __syncthreads();
    #pragma unroll
    for (int j = 0; j < 4; ++j) {
      int idx = t + j*T;
      if (idx < NN*32) {
        int n = idx >> 5, c = idx & 31;
        *(float4*)(&sXa[n*XSTR + c*4]) = m[j];
      }
    }
  }
  __syncthreads();

  // ---- P4: A2 build — feat2 = (self+nbr sums of X2 | bsum | pad), hi/lo ----
  for (int unit = t; unit < 64*16; unit += T) {
    int row = unit >> 4, c = unit & 15;
    int node = sSorted[row];
    float acc[8] = {0,0,0,0,0,0,0,0};
    if (node >= 0) {
      *(float4*)(&acc[0]) = *(const float4*)(&sXa[node*XSTR + c*8]);
      *(float4*)(&acc[4]) = *(const float4*)(&sXa[node*XSTR + c*8 + 4]);
      #pragma unroll
      for (int d = 0; d < DD; ++d) {
        int e = sEdges[node*DD + d];
        if (e >= 0) {
          float4 u0 = *(const float4*)(&sXa[e*XSTR + c*8]);
          float4 u1 = *(const float4*)(&sXa[e*XSTR + c*8 + 4]);
          acc[0]+=u0.x; acc[1]+=u0.y; acc[2]+=u0.z; acc[3]+=u0.w;
          acc[4]+=u1.x; acc[5]+=u1.y; acc[6]+=u1.z; acc[7]+=u1.w;
        }
      }
    }
    uint4 hi, lo; split8(acc, hi, lo);
    *(uint4*)(&sFA[row*FASTR + c*8]) = hi;
    *(uint4*)(&sFA[(64 + row)*FASTR + c*8]) = lo;
  }
  for (int idx = t; idx < 64*32; idx += T) {        // k = 128..159 tail (bsum | zeros)
    int row = idx >> 5, kk = idx & 31;
    int node = sSorted[row];
    float v = (node >= 0 && kk < BFD) ? sBsum[node*BFD + kk] : 0.f;
    u16 hi = f2bf(v);
    sFA[row*FASTR + 128 + kk] = hi;
    sFA[(64 + row)*FASTR + 128 + kk] = f2bf(v - bf2f(hi));
  }
  __syncthreads();

  // ---- P5: conv2 MFMA -> x3 (sXa) ----
  conv_mfma<KS2>(ws + W2T_OFF, b2, sFA, sXa, sSorted, sDeg, sPairD, sPairM, nP, wv, lane);
  __syncthreads();

  // ---- P6: pool2 IN PLACE: x4 = max(self, nbrs)(x3) * (deg>0) ----
  {
    float4 m[4];
    #pragma unroll
    for (int j = 0; j < 4; ++j) {
      int idx = t + j*T;
      if (idx < NN*32) {
        int n = idx >> 5, c = idx & 31;
        float4 v = {0.f, 0.f, 0.f, 0.f};
        if (sDeg[n] > 0) {
          v = *(const float4*)(&sXa[n*XSTR + c*4]);
          #pragma unroll
          for (int d = 0; d < DD; ++d) {
            int e = sEdges[n*DD + d];
            if (e >= 0) {
              float4 u = *(const float4*)(&sXa[e*XSTR + c*4]);
              v.x = fmaxf(v.x, u.x); v.y = fmaxf(v.y, u.y);
              v.z = fmaxf(v.z, u.z); v.w = fmaxf(v.w, u.w);
            }
          }
        }
        m[j] = v;
      }
    }
    __syncthreads();
    #pragma unroll
    for (int j = 0; j < 4; ++j) {
      int idx = t + j*T;
      if (idx < NN*32) {
        int n = idx >> 5, c = idx & 31;
        *(float4*)(&sXa[n*XSTR + c*4]) = m[j];
      }
    }
  }
  __syncthreads();

  // ---- P7: A3 build — gout features (x4 | bsum | pad), hi/lo ----
  for (int unit = t; unit < 64*16; unit += T) {
    int row = unit >> 4, c = unit & 15;
    int node = sSorted[row];
    float acc[8] = {0,0,0,0,0,0,0,0};
    if (node >= 0) {
      *(float4*)(&acc[0]) = *(const float4*)(&sXa[node*XSTR + c*8]);
      *(float4*)(&acc[4]) = *(const float4*)(&sXa[node*XSTR + c*8 + 4]);
    }
    uint4 hi, lo; split8(acc, hi, lo);
    *(uint4*)(&sFA[row*FASTR + c*8]) = hi;
    *(uint4*)(&sFA[(64 + row)*FASTR + c*8]) = lo;
  }
  for (int idx = t; idx < 64*32; idx += T) {
    int row = idx >> 5, kk = idx & 31;
    int node = sSorted[row];
    float v = (node >= 0 && kk < BFD) ? sBsum[node*BFD + kk] : 0.f;
    u16 hi = f2bf(v);
    sFA[row*FASTR + 128 + kk] = hi;
    sFA[(64 + row)*FASTR + 128 + kk] = f2bf(v - bf2f(hi));
  }
  __syncthreads();

  // ---- P8: gout MFMA: wave wv <-> n-tile wv; B hoisted to regs (reused 4 mt) ----
  {
    const int nt = wv, n16 = lane & 15, q = lane >> 4;
    const int h = nt*16 + n16;
    v8s bh[KS2], bl[KS2];
    #pragma unroll
    for (int ks = 0; ks < KS2; ++ks) {
      const size_t ub = WOT_OFF + ((size_t)(nt*KS2 + ks))*512;
      bh[ks] = ((const v8s*)(ws + ub))[lane];
      bl[ks] = ((const v8s*)(ws + LO_OFF + ub))[lane];
    }
    const float bb = bo[h];
    float part = 0.f;
    #pragma unroll 1
    for (int mt = 0; mt < 4; ++mt) {
      const int row = mt*16 + n16;
      v4f acc = {0.f, 0.f, 0.f, 0.f};
      #pragma unroll
      for (int ks = 0; ks < KS2; ++ks) {
        v8s ah = *(const v8s*)(&sFA[row*FASTR + ks*32 + q*8]);
        v8s al = *(const v8s*)(&sFA[(64 + row)*FASTR + ks*32 + q*8]);
        acc = __builtin_amdgcn_mfma_f32_16x16x32_bf16(ah, bh[ks], acc, 0, 0, 0);
        acc = __builtin_amdgcn_mfma_f32_16x16x32_bf16(al, bh[ks], acc, 0, 0, 0);
        acc = __builtin_amdgcn_mfma_f32_16x16x32_bf16(ah, bl[ks], acc, 0, 0, 0);
      }
      #pragma unroll
      for (int r = 0; r < 4; ++r) {
        int node = sSorted[mt*16 + q*4 + r];
        if (node >= 0 && sDeg[node] > 0) part += tanhf(acc[r] + bb);
      }
    }
    part += __shfl_xor(part, 16);
    part += __shfl_xor(part, 32);
    if (lane < 16) sPart[h] = part;
  }
  __syncthreads();

  // ---- P9: final FC + sigmoid ----
  if (t < CC) {
    float acc = bfc[t];
    #pragma unroll 16
    for (int i = 0; i < HH; ++i) acc = fmaf(sPart[i], Wfc[i*CC + t], acc);
    out[b*CC + t] = 1.f / (1.f + expf(-acc));
  }
}

extern "C" void kernel_launch(void* const* d_in, const int* in_sizes, int n_in,
                              void* d_out, int out_size, void* d_ws, size_t ws_size,
                              hipStream_t stream) {
  const float* atoms = (const float*)d_in[0];
  const float* bonds = (const float*)d_in[1];
  const int*   edges = (const int*)d_in[2];
  const float* W1  = (const float*)d_in[3];
  const float* b1  = (const float*)d_in[4];
  const float* W2  = (const float*)d_in[5];
  const float* b2  = (const float*)d_in[6];
  const float* Wo  = (const float*)d_in[7];
  const float* bo  = (const float*)d_in[8];
  const float* Wfc = (const float*)d_in[9];
  const float* bfc = (const float*)d_in[10];
  float* out = (float*)d_out;
  u16* ws = (u16*)d_ws;

  prep_kernel<<<(TOT_UNITS*512 + 255)/256, 256, 0, stream>>>(W1, W2, Wo, ws);
  ngfp_kernel<<<NB, T, 0, stream>>>(atoms, bonds, edges, b1, b2, bo, Wfc, bfc, ws, out);
}

// Round 8
// 254.951 us; speedup vs baseline: 3.3414x; 1.0271x over previous
//
#include <hip/hip_runtime.h>
#include <math.h>

typedef unsigned short u16;
typedef unsigned int   u32;
typedef short  v8s __attribute__((ext_vector_type(8)));   // 8 bf16 = 4 VGPRs (MFMA A/B frag)
typedef float  v4f __attribute__((ext_vector_type(4)));   // MFMA C/D frag

constexpr int NB=2048, NN=60, DD=6, AF=37, BFD=6, HH=128, CC=12;
constexpr int T = 512;          // 8 waves
constexpr int FASTR = 168;      // A-buffer row stride (bf16); rows 0..63 = hi, 64..127 = lo
constexpr int XSTR  = 132;      // X-buffer row stride (fp32): breaks pow2 bank alias
constexpr int ASTR  = 40;       // padded atom-staging stride (16B-aligned float4 rows)
constexpr int KS1 = 2;          // conv1: K=43 -> 64
constexpr int KS2 = 5;          // conv2/gout: K=134 -> 160
constexpr int MAXP = 32;

// d_ws layout: 1KB fragment blocks per (d, ntile, kstep); hi table, lo mirror at LO_OFF.
constexpr int W1T_UNITS = 6*8*KS1;   // 96
constexpr int W2T_UNITS = 6*8*KS2;   // 240
constexpr int WOT_UNITS = 8*KS2;     // 40
constexpr int TOT_UNITS = W1T_UNITS + W2T_UNITS + WOT_UNITS;   // 376 x2 = 770 KB
constexpr int W2T_OFF = W1T_UNITS*512;
constexpr int WOT_OFF = (W1T_UNITS+W2T_UNITS)*512;
constexpr int LO_OFF  = TOT_UNITS*512;

__device__ __forceinline__ u16 f2bf(float f) {
  u32 u = __float_as_uint(f);
  return (u16)((u + 0x7FFFu + ((u >> 16) & 1u)) >> 16);
}
__device__ __forceinline__ float bf2f(u16 h) { return __uint_as_float((u32)h << 16); }
__device__ __forceinline__ void split2(float a, float b, u32& hi, u32& lo) {
  u16 ha = f2bf(a), hb = f2bf(b);
  u16 la = f2bf(a - bf2f(ha)), lb = f2bf(b - bf2f(hb));
  hi = ((u32)hb << 16) | ha;
  lo = ((u32)lb << 16) | la;
}
__device__ __forceinline__ void split8(const float* v, uint4& hi, uint4& lo) {
  split2(v[0], v[1], hi.x, lo.x); split2(v[2], v[3], hi.y, lo.y);
  split2(v[4], v[5], hi.z, lo.z); split2(v[6], v[7], hi.w, lo.w);
}
__device__ __forceinline__ float fast_tanh(float x) {
  float e = __expf(2.f * x);            // inf-safe: x>>0 -> 1, x<<0 -> -1
  return 1.f - 2.f / (e + 1.f);
}

// ---- prep v2: one wave per unit. Lane l owns frag bytes l*16..+15.
// Loads: for fixed j, 16 lanes read 16 consecutive floats (64B segments). Stores: 16B/lane.
__global__ __launch_bounds__(256) void prep_kernel(
    const float* __restrict__ W1, const float* __restrict__ W2,
    const float* __restrict__ Wo, u16* __restrict__ ws)
{
  const int unit = blockIdx.x*4 + (threadIdx.x >> 6);
  if (unit >= TOT_UNITS) return;
  const int lane = threadIdx.x & 63;
  const int n16 = lane & 15, q = lane >> 4;
  const float* src; int K, nt, ks;
  if (unit < W1T_UNITS) {
    int d = unit / 16, rem = unit % 16; nt = rem >> 1; ks = rem & 1;
    src = W1 + (size_t)d*43*128; K = 43;
  } else if (unit < W1T_UNITS + W2T_UNITS) {
    int u = unit - W1T_UNITS; int d = u / 40, rem = u % 40; nt = rem / 5; ks = rem % 5;
    src = W2 + (size_t)d*134*128; K = 134;
  } else {
    int u = unit - (W1T_UNITS + W2T_UNITS); nt = u / 5; ks = u % 5;
    src = Wo; K = 134;
  }
  const int kbase = ks*32 + q*8;
  const int n = nt*16 + n16;
  u16 h8[8], l8[8];
  #pragma unroll
  for (int j = 0; j < 8; ++j) {
    int k = kbase + j;
    float v = (k < K) ? src[(size_t)k*128 + n] : 0.f;
    u16 h = f2bf(v);
    h8[j] = h; l8[j] = f2bf(v - bf2f(h));
  }
  uint4 H, L;
  H.x = (u32)h8[0] | ((u32)h8[1]<<16); H.y = (u32)h8[2] | ((u32)h8[3]<<16);
  H.z = (u32)h8[4] | ((u32)h8[5]<<16); H.w = (u32)h8[6] | ((u32)h8[7]<<16);
  L.x = (u32)l8[0] | ((u32)l8[1]<<16); L.y = (u32)l8[2] | ((u32)l8[3]<<16);
  L.z = (u32)l8[4] | ((u32)l8[5]<<16); L.w = (u32)l8[6] | ((u32)l8[7]<<16);
  ((uint4*)(ws + (size_t)unit*512))[lane] = H;
  ((uint4*)(ws + (size_t)(LO_OFF + unit*512)))[lane] = L;
}

// ---- conv via bf16x3 MFMA: wave owns a (degree, mtile) pair; A hi/lo in regs;
// nt-loop unrolled 4-wide for independent MFMA chains ----
template<int KSTEPS>
__device__ __forceinline__ void conv_mfma(
    const u16* __restrict__ wsW, const float* __restrict__ bias,
    const u16* sFA, float* sXout,
    const int* sSorted, const int* sDeg,
    const int* sPairD, const int* sPairM, int nP,
    int wv, int lane)
{
  const int n16 = lane & 15, q = lane >> 4;
  for (int p = wv; p < nP; p += 8) {
    const int d = sPairD[p], mt = sPairM[p];
    const int row = mt*16 + n16;
    int nodes[4];
    #pragma unroll
    for (int r = 0; r < 4; ++r) nodes[r] = sSorted[mt*16 + q*4 + r];
    if (d == 6) {                    // ref zeroes deg-6; not hit in practice
      #pragma unroll 1
      for (int nt = 0; nt < 8; ++nt) {
        const int h = nt*16 + n16;
        #pragma unroll
        for (int r = 0; r < 4; ++r)
          if (nodes[r] >= 0 && sDeg[nodes[r]] == 6) sXout[nodes[r]*XSTR + h] = 0.f;
      }
      continue;
    }
    v8s ah[KSTEPS], al[KSTEPS];
    #pragma unroll
    for (int ks = 0; ks < KSTEPS; ++ks) {
      ah[ks] = *(const v8s*)(&sFA[row*FASTR + ks*32 + q*8]);
      al[ks] = *(const v8s*)(&sFA[(64 + row)*FASTR + ks*32 + q*8]);
    }
    #pragma unroll 4
    for (int nt = 0; nt < 8; ++nt) {
      v4f acc = {0.f, 0.f, 0.f, 0.f};
      #pragma unroll
      for (int ks = 0; ks < KSTEPS; ++ks) {
        const size_t ub = ((size_t)((d*8 + nt)*KSTEPS + ks))*512;
        v8s bh = ((const v8s*)(wsW + ub))[lane];
        v8s bl = ((const v8s*)(wsW + LO_OFF + ub))[lane];
        acc = __builtin_amdgcn_mfma_f32_16x16x32_bf16(ah[ks], bh, acc, 0, 0, 0);
        acc = __builtin_amdgcn_mfma_f32_16x16x32_bf16(al[ks], bh, acc, 0, 0, 0);
        acc = __builtin_amdgcn_mfma_f32_16x16x32_bf16(ah[ks], bl, acc, 0, 0, 0);
      }
      const int h = nt*16 + n16;
      const float bb = bias[d*128 + h];
      #pragma unroll
      for (int r = 0; r < 4; ++r) {
        int node = nodes[r];
        if (node >= 0 && sDeg[node] == d)
          sXout[node*XSTR + h] = fmaxf(acc[r] + bb, 0.f);
      }
    }
  }
}

__global__ __launch_bounds__(T) void ngfp_kernel(
    const float* __restrict__ atoms, const float* __restrict__ bonds,
    const int*   __restrict__ edges,
    const float* __restrict__ b1, const float* __restrict__ b2,
    const float* __restrict__ bo,
    const float* __restrict__ Wfc, const float* __restrict__ bfc,
    const u16*   __restrict__ ws,
    float* __restrict__ out)
{
  __shared__ u16   sFA[128*FASTR];   // 43008 B — A-tiles hi (rows 0..63) + lo (64..127)
  __shared__ float sXa[NN*XSTR];     // 31680 B — atom staging / X1/X2/x3 (fp32)
  __shared__ float sBsum[NN*BFD];
  __shared__ int  sEdges[NN*DD];
  __shared__ int  sDeg[NN];
  __shared__ int  sSorted[64];
  __shared__ int  sRowStart[8];
  __shared__ int  sCnt[8];
  __shared__ int  sPairD[MAXP];
  __shared__ int  sPairM[MAXP];
  __shared__ int  sNP;
  __shared__ float sPart[HH];
  __shared__ float sRed[96];
  // total ~79.0 KB -> 2 blocks/CU, 16 waves/CU

  float* const sAtomsP = sXa;   // stride-40 padded staging, dead once A1 built

  const int b = blockIdx.x;
  const int t = threadIdx.x;
  const int wv = t >> 6;
  const int lane = t & 63;

  // ---- P0: stage edges, padded atoms, bond-sums; degree; sort; pair list ----
  for (int i = t; i < NN*DD; i += T) sEdges[i] = edges[b*NN*DD + i];
  for (int i = t; i < NN*ASTR; i += T) {
    int n = i / ASTR, f = i - n*ASTR;
    sAtomsP[i] = (f < AF) ? atoms[b*NN*AF + n*AF + f] : 0.f;
  }
  for (int i = t; i < NN*BFD; i += T) {
    int n = i / BFD, f = i - n*BFD;
    const float* bp = bonds + ((size_t)(b*NN + n)*DD)*BFD + f;
    float s = 0.f;
    #pragma unroll
    for (int d = 0; d < DD; ++d) s += bp[d*BFD];
    sBsum[i] = s;
  }
  __syncthreads();
  if (t < NN) {
    int dg = 0;
    #pragma unroll
    for (int d = 0; d < DD; ++d) dg += (sEdges[t*DD + d] != -1) ? 1 : 0;
    sDeg[t] = dg;
  }
  __syncthreads();
  if (t < 7) {
    int c = 0;
    for (int n = 0; n < NN; ++n) c += (sDeg[n] == t) ? 1 : 0;
    sCnt[t] = c;
  }
  __syncthreads();
  if (t == 0) {
    int rs = 0;
    for (int d = 0; d < 7; ++d) { sRowStart[d] = rs; rs += sCnt[d]; }
    sRowStart[7] = rs;
    int np = 0;
    for (int d = 0; d < 7; ++d) {
      int r0 = sRowStart[d], r1 = sRowStart[d+1];
      if (r0 == r1) continue;
      for (int mt = r0 >> 4; mt < ((r1 + 15) >> 4); ++mt) {
        sPairD[np] = d; sPairM[np] = mt; ++np;
      }
    }
    sNP = np;
  }
  __syncthreads();
  if (t < 7) {
    int idx = sRowStart[t];
    for (int n = 0; n < NN; ++n) if (sDeg[n] == t) sSorted[idx++] = n;
  }
  if (t == 0) { sSorted[60] = sSorted[61] = sSorted[62] = sSorted[63] = -1; }
  __syncthreads();
  const int nP = sNP;

  // ---- P1: A1 build — vectorized: padded stride-40 rows give aligned float4s ----
  {
    const int row = t >> 3, c = t & 7;     // 512 units exactly
    const int node = sSorted[row];
    float acc[8] = {0,0,0,0,0,0,0,0};
    if (node >= 0) {
      if (c < 5) {
        const float* p = sAtomsP + node*ASTR + c*8;
        float4 a0 = *(const float4*)p, a1 = *(const float4*)(p + 4);
        #pragma unroll
        for (int d = 0; d < DD; ++d) {
          int e = sEdges[node*DD + d];
          if (e >= 0) {
            const float* pe = sAtomsP + e*ASTR + c*8;
            float4 u0 = *(const float4*)pe, u1 = *(const float4*)(pe + 4);
            a0.x+=u0.x; a0.y+=u0.y; a0.z+=u0.z; a0.w+=u0.w;
            a1.x+=u1.x; a1.y+=u1.y; a1.z+=u1.z; a1.w+=u1.w;
          }
        }
        acc[0]=a0.x; acc[1]=a0.y; acc[2]=a0.z; acc[3]=a0.w;
        acc[4]=a1.x; acc[5]=a1.y; acc[6]=a1.z; acc[7]=a1.w;
      }
      if (c == 4) {        // k=37..39 -> bsum[0..2] (pad zeros were summed; overwrite)
        acc[5] = sBsum[node*BFD + 0];
        acc[6] = sBsum[node*BFD + 1];
        acc[7] = sBsum[node*BFD + 2];
      } else if (c == 5) { // k=40..42 -> bsum[3..5]
        acc[0] = sBsum[node*BFD + 3];
        acc[1] = sBsum[node*BFD + 4];
        acc[2] = sBsum[node*BFD + 5];
      }
    }
    uint4 hi, lo; split8(acc, hi, lo);
    *(uint4*)(&sFA[row*FASTR + c*8]) = hi;
    *(uint4*)(&sFA[(64 + row)*FASTR + c*8]) = lo;
  }
  __syncthreads();

  // ---- P2: conv1 MFMA -> X1 (sXa fp32) ----
  conv_mfma<KS1>(ws, b1, sFA, sXa, sSorted, sDeg, sPairD, sPairM, nP, wv, lane);
  __syncthreads();

  // ---- P3: pool1 IN PLACE: X2 = max(self, nbrs)(X1) * (deg>0) ----
  {
    float4 m[4];
    #pragma unroll
    for (int j = 0; j < 4; ++j) {
      int idx = t + j*T;
      if (idx < NN*32) {
        int n = idx >> 5, c = idx & 31;
        float4 v = {0.f, 0.f, 0.f, 0.f};
        if (sDeg[n] > 0) {
          v = *(const float4*)(&sXa[n*XSTR + c*4]);
          #pragma unroll
          for (int d = 0; d < DD; ++d) {
            int e = sEdges[n*DD + d];
            if (e >= 0) {
              float4 u = *(const float4*)(&sXa[e*XSTR + c*4]);
              v.x = fmaxf(v.x, u.x); v.y = fmaxf(v.y, u.y);
              v.z = fmaxf(v.z, u.z); v.w = fmaxf(v.w, u.w);
            }
          }
        }
        m[j] = v;
      }
    }
    __syncthreads();
    #pragma unroll
    for (int j = 0; j < 4; ++j) {
      int idx = t + j*T;
      if (idx < NN*32) {
        int n = idx >> 5, c = idx & 31;
        *(float4*)(&sXa[n*XSTR + c*4]) = m[j];
      }
    }
  }
  __syncthreads();

  // ---- P4: A2 build — feat2 = (self+nbr sums of X2 | bsum | pad), hi/lo ----
  for (int unit = t; unit < 64*16; unit += T) {
    int row = unit >> 4, c = unit & 15;
    int node = sSorted[row];
    float acc[8] = {0,0,0,0,0,0,0,0};
    if (node >= 0) {
      *(float4*)(&acc[0]) = *(const float4*)(&sXa[node*XSTR + c*8]);
      *(float4*)(&acc[4]) = *(const float4*)(&sXa[node*XSTR + c*8 + 4]);
      #pragma unroll
      for (int d = 0; d < DD; ++d) {
        int e = sEdges[node*DD + d];
        if (e >= 0) {
          float4 u0 = *(const float4*)(&sXa[e*XSTR + c*8]);
          float4 u1 = *(const float4*)(&sXa[e*XSTR + c*8 + 4]);
          acc[0]+=u0.x; acc[1]+=u0.y; acc[2]+=u0.z; acc[3]+=u0.w;
          acc[4]+=u1.x; acc[5]+=u1.y; acc[6]+=u1.z; acc[7]+=u1.w;
        }
      }
    }
    uint4 hi, lo; split8(acc, hi, lo);
    *(uint4*)(&sFA[row*FASTR + c*8]) = hi;
    *(uint4*)(&sFA[(64 + row)*FASTR + c*8]) = lo;
  }
  for (int idx = t; idx < 64*32; idx += T) {        // k = 128..159 tail (bsum | zeros)
    int row = idx >> 5, kk = idx & 31;
    int node = sSorted[row];
    float v = (node >= 0 && kk < BFD) ? sBsum[node*BFD + kk] : 0.f;
    u16 hi = f2bf(v);
    sFA[row*FASTR + 128 + kk] = hi;
    sFA[(64 + row)*FASTR + 128 + kk] = f2bf(v - bf2f(hi));
  }
  __syncthreads();

  // ---- P5: conv2 MFMA -> x3 (sXa) ----
  conv_mfma<KS2>(ws + W2T_OFF, b2, sFA, sXa, sSorted, sDeg, sPairD, sPairM, nP, wv, lane);
  __syncthreads();

  // ---- P6+P7 FUSED: x4 = max(self,nbrs)(x3)*(deg>0), written straight to A3 hi/lo ----
  for (int unit = t; unit < 64*16; unit += T) {
    int row = unit >> 4, c = unit & 15;
    int node = sSorted[row];
    float acc[8] = {0,0,0,0,0,0,0,0};
    if (node >= 0 && sDeg[node] > 0) {
      float4 a0 = *(const float4*)(&sXa[node*XSTR + c*8]);
      float4 a1 = *(const float4*)(&sXa[node*XSTR + c*8 + 4]);
      #pragma unroll
      for (int d = 0; d < DD; ++d) {
        int e = sEdges[node*DD + d];
        if (e >= 0) {
          float4 u0 = *(const float4*)(&sXa[e*XSTR + c*8]);
          float4 u1 = *(const float4*)(&sXa[e*XSTR + c*8 + 4]);
          a0.x = fmaxf(a0.x, u0.x); a0.y = fmaxf(a0.y, u0.y);
          a0.z = fmaxf(a0.z, u0.z); a0.w = fmaxf(a0.w, u0.w);
          a1.x = fmaxf(a1.x, u1.x); a1.y = fmaxf(a1.y, u1.y);
          a1.z = fmaxf(a1.z, u1.z); a1.w = fmaxf(a1.w, u1.w);
        }
      }
      acc[0]=a0.x; acc[1]=a0.y; acc[2]=a0.z; acc[3]=a0.w;
      acc[4]=a1.x; acc[5]=a1.y; acc[6]=a1.z; acc[7]=a1.w;
    }
    uint4 hi, lo; split8(acc, hi, lo);
    *(uint4*)(&sFA[row*FASTR + c*8]) = hi;
    *(uint4*)(&sFA[(64 + row)*FASTR + c*8]) = lo;
  }
  for (int idx = t; idx < 64*32; idx += T) {
    int row = idx >> 5, kk = idx & 31;
    int node = sSorted[row];
    float v = (node >= 0 && kk < BFD) ? sBsum[node*BFD + kk] : 0.f;
    u16 hi = f2bf(v);
    sFA[row*FASTR + 128 + kk] = hi;
    sFA[(64 + row)*FASTR + 128 + kk] = f2bf(v - bf2f(hi));
  }
  __syncthreads();

  // ---- P8: gout MFMA: wave wv <-> n-tile wv; B hoisted to regs ----
  {
    const int nt = wv, n16 = lane & 15, q = lane >> 4;
    const int h = nt*16 + n16;
    v8s bh[KS2], bl[KS2];
    #pragma unroll
    for (int ks = 0; ks < KS2; ++ks) {
      const size_t ub = WOT_OFF + ((size_t)(nt*KS2 + ks))*512;
      bh[ks] = ((const v8s*)(ws + ub))[lane];
      bl[ks] = ((const v8s*)(ws + LO_OFF + ub))[lane];
    }
    const float bb = bo[h];
    float part = 0.f;
    #pragma unroll 2
    for (int mt = 0; mt < 4; ++mt) {
      const int row = mt*16 + n16;
      v4f acc = {0.f, 0.f, 0.f, 0.f};
      #pragma unroll
      for (int ks = 0; ks < KS2; ++ks) {
        v8s ah = *(const v8s*)(&sFA[row*FASTR + ks*32 + q*8]);
        v8s al = *(const v8s*)(&sFA[(64 + row)*FASTR + ks*32 + q*8]);
        acc = __builtin_amdgcn_mfma_f32_16x16x32_bf16(ah, bh[ks], acc, 0, 0, 0);
        acc = __builtin_amdgcn_mfma_f32_16x16x32_bf16(al, bh[ks], acc, 0, 0, 0);
        acc = __builtin_amdgcn_mfma_f32_16x16x32_bf16(ah, bl[ks], acc, 0, 0, 0);
      }
      #pragma unroll
      for (int r = 0; r < 4; ++r) {
        int node = sSorted[mt*16 + q*4 + r];
        if (node >= 0 && sDeg[node] > 0) part += fast_tanh(acc[r] + bb);
      }
    }
    part += __shfl_xor(part, 16);
    part += __shfl_xor(part, 32);
    if (lane < 16) sPart[h] = part;
  }
  __syncthreads();

  // ---- P9: final FC + sigmoid (parallel: 96 threads, 16 FMAs each, reduce) ----
  if (t < 96) {
    const int c = t >> 3, s = t & 7;
    float acc = 0.f;
    #pragma unroll
    for (int i = 0; i < 16; ++i) {
      int ii = s*16 + i;
      acc = fmaf(sPart[ii], Wfc[ii*CC + c], acc);
    }
    sRed[t] = acc;
  }
  __syncthreads();
  if (t < CC) {
    float acc = bfc[t];
    #pragma unroll
    for (int s = 0; s < 8; ++s) acc += sRed[t*8 + s];
    out[b*CC + t] = 1.f / (1.f + __expf(-acc));
  }
}

extern "C" void kernel_launch(void* const* d_in, const int* in_sizes, int n_in,
                              void* d_out, int out_size, void* d_ws, size_t ws_size,
                              hipStream_t stream) {
  const float* atoms = (const float*)d_in[0];
  const float* bonds = (const float*)d_in[1];
  const int*   edges = (const int*)d_in[2];
  const float* W1  = (const float*)d_in[3];
  const float* b1  = (const float*)d_in[4];
  const float* W2  = (const float*)d_in[5];
  const float* b2  = (const float*)d_in[6];
  const float* Wo  = (const float*)d_in[7];
  const float* bo  = (const float*)d_in[8];
  const float* Wfc = (const float*)d_in[9];
  const float* bfc = (const float*)d_in[10];
  float* out = (float*)d_out;
  u16* ws = (u16*)d_ws;

  prep_kernel<<<(TOT_UNITS + 3)/4, 256, 0, stream>>>(W1, W2, Wo, ws);
  ngfp_kernel<<<NB, T, 0, stream>>>(atoms, bonds, edges, b1, b2, bo, Wfc, bfc, ws, out);
}

// Round 9
// 251.878 us; speedup vs baseline: 3.3821x; 1.0122x over previous
//
#include <hip/hip_runtime.h>
#include <math.h>

typedef unsigned short u16;
typedef unsigned int   u32;
typedef short  v8s __attribute__((ext_vector_type(8)));   // 8 bf16 = 4 VGPRs (MFMA A/B frag)
typedef float  v4f __attribute__((ext_vector_type(4)));   // MFMA C/D frag

constexpr int NB=2048, NN=60, DD=6, AF=37, BFD=6, HH=128, CC=12;
constexpr int T = 512;          // 8 waves
constexpr int FASTR = 168;      // A-buffer row stride (bf16); rows 0..63 = hi, 64..127 = lo
constexpr int XSTR  = 132;      // X-buffer row stride (fp32): breaks pow2 bank alias
constexpr int ASTR  = 44;       // atom staging stride: 44 dwords = shift 12 mod 32 banks
constexpr int KS1 = 2;          // conv1: K=43 -> 64
constexpr int KS2 = 5;          // conv2/gout: K=134 -> 160
constexpr int MAXP = 32;

// d_ws layout: 1KB fragment blocks per (d, ntile, kstep); hi table, lo mirror at LO_OFF.
constexpr int W1T_UNITS = 6*8*KS1;   // 96
constexpr int W2T_UNITS = 6*8*KS2;   // 240
constexpr int WOT_UNITS = 8*KS2;     // 40
constexpr int TOT_UNITS = W1T_UNITS + W2T_UNITS + WOT_UNITS;   // 376 x2 = 770 KB
constexpr int W2T_OFF = W1T_UNITS*512;
constexpr int WOT_OFF = (W1T_UNITS+W2T_UNITS)*512;
constexpr int LO_OFF  = TOT_UNITS*512;

__device__ __forceinline__ u16 f2bf(float f) {
  u32 u = __float_as_uint(f);
  return (u16)((u + 0x7FFFu + ((u >> 16) & 1u)) >> 16);
}
__device__ __forceinline__ float bf2f(u16 h) { return __uint_as_float((u32)h << 16); }

#if defined(__has_builtin)
#if __has_builtin(__builtin_amdgcn_cvt_pk_bf16_f32)
#define HAVE_PK_BF16 1
#endif
#endif

// split pair (a,b) -> packed hi bf16x2 (a low, b high) and lo (residual) bf16x2
__device__ __forceinline__ void split2(float a, float b, u32& hi, u32& lo) {
#ifdef HAVE_PK_BF16
  typedef __bf16 bf16x2 __attribute__((ext_vector_type(2)));
  bf16x2 h2 = __builtin_amdgcn_cvt_pk_bf16_f32(a, b);     // D[15:0]=cvt(a), D[31:16]=cvt(b), RNE
  hi = __builtin_bit_cast(u32, h2);
  float ha = __uint_as_float(hi << 16);
  float hb = __uint_as_float(hi & 0xFFFF0000u);
  bf16x2 l2 = __builtin_amdgcn_cvt_pk_bf16_f32(a - ha, b - hb);
  lo = __builtin_bit_cast(u32, l2);
#else
  u16 ha = f2bf(a), hb = f2bf(b);
  u16 la = f2bf(a - bf2f(ha)), lb = f2bf(b - bf2f(hb));
  hi = ((u32)hb << 16) | ha;
  lo = ((u32)lb << 16) | la;
#endif
}
__device__ __forceinline__ void split8(const float* v, uint4& hi, uint4& lo) {
  split2(v[0], v[1], hi.x, lo.x); split2(v[2], v[3], hi.y, lo.y);
  split2(v[4], v[5], hi.z, lo.z); split2(v[6], v[7], hi.w, lo.w);
}
__device__ __forceinline__ float fast_tanh(float x) {
  float e = __expf(2.f * x);            // inf-safe: x>>0 -> 1, x<<0 -> -1
  return 1.f - 2.f / (e + 1.f);
}

// ---- prep v3: ONE 64-thread block per unit (376 blocks). Lane l owns frag bytes
// l*16..+15. Loads: for fixed j, 16 lanes read 16 consecutive floats (64B segments).
__global__ __launch_bounds__(64) void prep_kernel(
    const float* __restrict__ W1, const float* __restrict__ W2,
    const float* __restrict__ Wo, u16* __restrict__ ws)
{
  const int unit = blockIdx.x;
  if (unit >= TOT_UNITS) return;
  const int lane = threadIdx.x & 63;
  const int n16 = lane & 15, q = lane >> 4;
  const float* src; int K, nt, ks;
  if (unit < W1T_UNITS) {
    int d = unit / 16, rem = unit % 16; nt = rem >> 1; ks = rem & 1;
    src = W1 + (size_t)d*43*128; K = 43;
  } else if (unit < W1T_UNITS + W2T_UNITS) {
    int u = unit - W1T_UNITS; int d = u / 40, rem = u % 40; nt = rem / 5; ks = rem % 5;
    src = W2 + (size_t)d*134*128; K = 134;
  } else {
    int u = unit - (W1T_UNITS + W2T_UNITS); nt = u / 5; ks = u % 5;
    src = Wo; K = 134;
  }
  const int kbase = ks*32 + q*8;
  const int n = nt*16 + n16;
  float v8[8];
  #pragma unroll
  for (int j = 0; j < 8; ++j) {
    int k = kbase + j;
    v8[j] = (k < K) ? src[(size_t)k*128 + n] : 0.f;
  }
  uint4 H, L;
  split8(v8, H, L);
  ((uint4*)(ws + (size_t)unit*512))[lane] = H;
  ((uint4*)(ws + (size_t)(LO_OFF + unit*512)))[lane] = L;
}

// ---- conv via bf16x3 MFMA: wave owns a (degree, mtile) pair; A hi/lo in regs;
// nt-loop unrolled 4-wide for independent MFMA chains ----
template<int KSTEPS>
__device__ __forceinline__ void conv_mfma(
    const u16* __restrict__ wsW, const float* __restrict__ bias,
    const u16* sFA, float* sXout,
    const int* sSorted, const int* sDeg,
    const int* sPairD, const int* sPairM, int nP,
    int wv, int lane)
{
  const int n16 = lane & 15, q = lane >> 4;
  for (int p = wv; p < nP; p += 8) {
    const int d = sPairD[p], mt = sPairM[p];
    const int row = mt*16 + n16;
    int nodes[4];
    #pragma unroll
    for (int r = 0; r < 4; ++r) nodes[r] = sSorted[mt*16 + q*4 + r];
    if (d == 6) {                    // ref zeroes deg-6; not hit in practice
      #pragma unroll 1
      for (int nt = 0; nt < 8; ++nt) {
        const int h = nt*16 + n16;
        #pragma unroll
        for (int r = 0; r < 4; ++r)
          if (nodes[r] >= 0 && sDeg[nodes[r]] == 6) sXout[nodes[r]*XSTR + h] = 0.f;
      }
      continue;
    }
    v8s ah[KSTEPS], al[KSTEPS];
    #pragma unroll
    for (int ks = 0; ks < KSTEPS; ++ks) {
      ah[ks] = *(const v8s*)(&sFA[row*FASTR + ks*32 + q*8]);
      al[ks] = *(const v8s*)(&sFA[(64 + row)*FASTR + ks*32 + q*8]);
    }
    #pragma unroll 4
    for (int nt = 0; nt < 8; ++nt) {
      v4f acc = {0.f, 0.f, 0.f, 0.f};
      #pragma unroll
      for (int ks = 0; ks < KSTEPS; ++ks) {
        const size_t ub = ((size_t)((d*8 + nt)*KSTEPS + ks))*512;
        v8s bh = ((const v8s*)(wsW + ub))[lane];
        v8s bl = ((const v8s*)(wsW + LO_OFF + ub))[lane];
        acc = __builtin_amdgcn_mfma_f32_16x16x32_bf16(ah[ks], bh, acc, 0, 0, 0);
        acc = __builtin_amdgcn_mfma_f32_16x16x32_bf16(al[ks], bh, acc, 0, 0, 0);
        acc = __builtin_amdgcn_mfma_f32_16x16x32_bf16(ah[ks], bl, acc, 0, 0, 0);
      }
      const int h = nt*16 + n16;
      const float bb = bias[d*128 + h];
      #pragma unroll
      for (int r = 0; r < 4; ++r) {
        int node = nodes[r];
        if (node >= 0 && sDeg[node] == d)
          sXout[node*XSTR + h] = fmaxf(acc[r] + bb, 0.f);
      }
    }
  }
}

__global__ __launch_bounds__(T) void ngfp_kernel(
    const float* __restrict__ atoms, const float* __restrict__ bonds,
    const int*   __restrict__ edges,
    const float* __restrict__ b1, const float* __restrict__ b2,
    const float* __restrict__ bo,
    const float* __restrict__ Wfc, const float* __restrict__ bfc,
    const u16*   __restrict__ ws,
    float* __restrict__ out)
{
  __shared__ u16   sFA[128*FASTR];   // 43008 B — A-tiles hi (rows 0..63) + lo (64..127)
  __shared__ float sXa[NN*XSTR];     // 31680 B — atom staging / X1/X2/x3 (fp32)
  __shared__ float sBsum[NN*BFD];
  __shared__ int  sEdges[NN*DD];
  __shared__ int  sDeg[NN];
  __shared__ int  sSorted[64];
  __shared__ int  sRowStart[8];
  __shared__ int  sCnt[8];
  __shared__ int  sPairD[MAXP];
  __shared__ int  sPairM[MAXP];
  __shared__ int  sNP;
  __shared__ float sPart[HH];
  __shared__ float sRed[96];
  // total ~79.0 KB -> 2 blocks/CU, 16 waves/CU

  float* const sAtomsP = sXa;   // stride-44 padded staging, dead once A1 built

  const int b = blockIdx.x;
  const int t = threadIdx.x;
  const int wv = t >> 6;
  const int lane = t & 63;

  // ---- P0: stage edges, padded atoms, bond-sums; degree; sort; pair list ----
  for (int i = t; i < NN*DD; i += T) sEdges[i] = edges[b*NN*DD + i];
  for (int i = t; i < NN*ASTR; i += T) {
    int n = i / ASTR, f = i - n*ASTR;
    sAtomsP[i] = (f < AF) ? atoms[b*NN*AF + n*AF + f] : 0.f;
  }
  for (int i = t; i < NN*BFD; i += T) {
    int n = i / BFD, f = i - n*BFD;
    const float* bp = bonds + ((size_t)(b*NN + n)*DD)*BFD + f;
    float s = 0.f;
    #pragma unroll
    for (int d = 0; d < DD; ++d) s += bp[d*BFD];
    sBsum[i] = s;
  }
  __syncthreads();
  if (t < NN) {
    int dg = 0;
    #pragma unroll
    for (int d = 0; d < DD; ++d) dg += (sEdges[t*DD + d] != -1) ? 1 : 0;
    sDeg[t] = dg;
  }
  __syncthreads();
  if (t < 7) {
    int c = 0;
    for (int n = 0; n < NN; ++n) c += (sDeg[n] == t) ? 1 : 0;
    sCnt[t] = c;
  }
  __syncthreads();
  if (t == 0) {
    int rs = 0;
    for (int d = 0; d < 7; ++d) { sRowStart[d] = rs; rs += sCnt[d]; }
    sRowStart[7] = rs;
    int np = 0;
    for (int d = 0; d < 7; ++d) {
      int r0 = sRowStart[d], r1 = sRowStart[d+1];
      if (r0 == r1) continue;
      for (int mt = r0 >> 4; mt < ((r1 + 15) >> 4); ++mt) {
        sPairD[np] = d; sPairM[np] = mt; ++np;
      }
    }
    sNP = np;
  }
  __syncthreads();
  if (t < 7) {
    int idx = sRowStart[t];
    for (int n = 0; n < NN; ++n) if (sDeg[n] == t) sSorted[idx++] = n;
  }
  if (t == 0) { sSorted[60] = sSorted[61] = sSorted[62] = sSorted[63] = -1; }
  __syncthreads();
  const int nP = sNP;

  // ---- P1: A1 build — padded stride-44 rows give aligned float4 gathers ----
  {
    const int row = t >> 3, c = t & 7;     // 512 units exactly
    const int node = sSorted[row];
    float acc[8] = {0,0,0,0,0,0,0,0};
    if (node >= 0) {
      if (c < 5) {
        const float* p = sAtomsP + node*ASTR + c*8;
        float4 a0 = *(const float4*)p, a1 = *(const float4*)(p + 4);
        #pragma unroll
        for (int d = 0; d < DD; ++d) {
          int e = sEdges[node*DD + d];
          if (e >= 0) {
            const float* pe = sAtomsP + e*ASTR + c*8;
            float4 u0 = *(const float4*)pe, u1 = *(const float4*)(pe + 4);
            a0.x+=u0.x; a0.y+=u0.y; a0.z+=u0.z; a0.w+=u0.w;
            a1.x+=u1.x; a1.y+=u1.y; a1.z+=u1.z; a1.w+=u1.w;
          }
        }
        acc[0]=a0.x; acc[1]=a0.y; acc[2]=a0.z; acc[3]=a0.w;
        acc[4]=a1.x; acc[5]=a1.y; acc[6]=a1.z; acc[7]=a1.w;
      }
      if (c == 4) {        // k=37..39 -> bsum[0..2] (pad zeros were summed; overwrite)
        acc[5] = sBsum[node*BFD + 0];
        acc[6] = sBsum[node*BFD + 1];
        acc[7] = sBsum[node*BFD + 2];
      } else if (c == 5) { // k=40..42 -> bsum[3..5]
        acc[0] = sBsum[node*BFD + 3];
        acc[1] = sBsum[node*BFD + 4];
        acc[2] = sBsum[node*BFD + 5];
      }
    }
    uint4 hi, lo; split8(acc, hi, lo);
    *(uint4*)(&sFA[row*FASTR + c*8]) = hi;
    *(uint4*)(&sFA[(64 + row)*FASTR + c*8]) = lo;
  }
  __syncthreads();

  // ---- P2: conv1 MFMA -> X1 (sXa fp32) ----
  conv_mfma<KS1>(ws, b1, sFA, sXa, sSorted, sDeg, sPairD, sPairM, nP, wv, lane);
  __syncthreads();

  // ---- P3: pool1 IN PLACE: X2 = max(self, nbrs)(X1) * (deg>0) ----
  {
    float4 m[4];
    #pragma unroll
    for (int j = 0; j < 4; ++j) {
      int idx = t + j*T;
      if (idx < NN*32) {
        int n = idx >> 5, c = idx & 31;
        float4 v = {0.f, 0.f, 0.f, 0.f};
        if (sDeg[n] > 0) {
          v = *(const float4*)(&sXa[n*XSTR + c*4]);
          #pragma unroll
          for (int d = 0; d < DD; ++d) {
            int e = sEdges[n*DD + d];
            if (e >= 0) {
              float4 u = *(const float4*)(&sXa[e*XSTR + c*4]);
              v.x = fmaxf(v.x, u.x); v.y = fmaxf(v.y, u.y);
              v.z = fmaxf(v.z, u.z); v.w = fmaxf(v.w, u.w);
            }
          }
        }
        m[j] = v;
      }
    }
    __syncthreads();
    #pragma unroll
    for (int j = 0; j < 4; ++j) {
      int idx = t + j*T;
      if (idx < NN*32) {
        int n = idx >> 5, c = idx & 31;
        *(float4*)(&sXa[n*XSTR + c*4]) = m[j];
      }
    }
  }
  __syncthreads();

  // ---- P4: A2 build — feat2 = (self+nbr sums of X2 | bsum | pad), hi/lo ----
  for (int unit = t; unit < 64*16; unit += T) {
    int row = unit >> 4, c = unit & 15;
    int node = sSorted[row];
    float acc[8] = {0,0,0,0,0,0,0,0};
    if (node >= 0) {
      *(float4*)(&acc[0]) = *(const float4*)(&sXa[node*XSTR + c*8]);
      *(float4*)(&acc[4]) = *(const float4*)(&sXa[node*XSTR + c*8 + 4]);
      #pragma unroll
      for (int d = 0; d < DD; ++d) {
        int e = sEdges[node*DD + d];
        if (e >= 0) {
          float4 u0 = *(const float4*)(&sXa[e*XSTR + c*8]);
          float4 u1 = *(const float4*)(&sXa[e*XSTR + c*8 + 4]);
          acc[0]+=u0.x; acc[1]+=u0.y; acc[2]+=u0.z; acc[3]+=u0.w;
          acc[4]+=u1.x; acc[5]+=u1.y; acc[6]+=u1.z; acc[7]+=u1.w;
        }
      }
    }
    uint4 hi, lo; split8(acc, hi, lo);
    *(uint4*)(&sFA[row*FASTR + c*8]) = hi;
    *(uint4*)(&sFA[(64 + row)*FASTR + c*8]) = lo;
  }
  // K-tail k=128..159: part 0 holds bsum(6)+zeros(2); parts 1..3 all zero (uint4 stores)
  if (t < 256) {
    int row = t >> 2, part = t & 3;
    uint4 hi = {0,0,0,0}, lo = {0,0,0,0};
    if (part == 0) {
      int node = sSorted[row];
      float acc[8] = {0,0,0,0,0,0,0,0};
      if (node >= 0) {
        #pragma unroll
        for (int j = 0; j < BFD; ++j) acc[j] = sBsum[node*BFD + j];
      }
      split8(acc, hi, lo);
    }
    *(uint4*)(&sFA[row*FASTR + 128 + part*8]) = hi;
    *(uint4*)(&sFA[(64 + row)*FASTR + 128 + part*8]) = lo;
  }
  __syncthreads();

  // ---- P5: conv2 MFMA -> x3 (sXa) ----
  conv_mfma<KS2>(ws + W2T_OFF, b2, sFA, sXa, sSorted, sDeg, sPairD, sPairM, nP, wv, lane);
  __syncthreads();

  // ---- P6+P7 FUSED: x4 = max(self,nbrs)(x3)*(deg>0), written straight to A3 hi/lo ----
  for (int unit = t; unit < 64*16; unit += T) {
    int row = unit >> 4, c = unit & 15;
    int node = sSorted[row];
    float acc[8] = {0,0,0,0,0,0,0,0};
    if (node >= 0 && sDeg[node] > 0) {
      float4 a0 = *(const float4*)(&sXa[node*XSTR + c*8]);
      float4 a1 = *(const float4*)(&sXa[node*XSTR + c*8 + 4]);
      #pragma unroll
      for (int d = 0; d < DD; ++d) {
        int e = sEdges[node*DD + d];
        if (e >= 0) {
          float4 u0 = *(const float4*)(&sXa[e*XSTR + c*8]);
          float4 u1 = *(const float4*)(&sXa[e*XSTR + c*8 + 4]);
          a0.x = fmaxf(a0.x, u0.x); a0.y = fmaxf(a0.y, u0.y);
          a0.z = fmaxf(a0.z, u0.z); a0.w = fmaxf(a0.w, u0.w);
          a1.x = fmaxf(a1.x, u1.x); a1.y = fmaxf(a1.y, u1.y);
          a1.z = fmaxf(a1.z, u1.z); a1.w = fmaxf(a1.w, u1.w);
        }
      }
      acc[0]=a0.x; acc[1]=a0.y; acc[2]=a0.z; acc[3]=a0.w;
      acc[4]=a1.x; acc[5]=a1.y; acc[6]=a1.z; acc[7]=a1.w;
    }
    uint4 hi, lo; split8(acc, hi, lo);
    *(uint4*)(&sFA[row*FASTR + c*8]) = hi;
    *(uint4*)(&sFA[(64 + row)*FASTR + c*8]) = lo;
  }
  if (t < 256) {
    int row = t >> 2, part = t & 3;
    uint4 hi = {0,0,0,0}, lo = {0,0,0,0};
    if (part == 0) {
      int node = sSorted[row];
      float acc[8] = {0,0,0,0,0,0,0,0};
      if (node >= 0) {
        #pragma unroll
        for (int j = 0; j < BFD; ++j) acc[j] = sBsum[node*BFD + j];
      }
      split8(acc, hi, lo);
    }
    *(uint4*)(&sFA[row*FASTR + 128 + part*8]) = hi;
    *(uint4*)(&sFA[(64 + row)*FASTR + 128 + part*8]) = lo;
  }
  __syncthreads();

  // ---- P8: gout MFMA: wave wv <-> n-tile wv; B hoisted to regs ----
  {
    const int nt = wv, n16 = lane & 15, q = lane >> 4;
    const int h = nt*16 + n16;
    v8s bh[KS2], bl[KS2];
    #pragma unroll
    for (int ks = 0; ks < KS2; ++ks) {
      const size_t ub = WOT_OFF + ((size_t)(nt*KS2 + ks))*512;
      bh[ks] = ((const v8s*)(ws + ub))[lane];
      bl[ks] = ((const v8s*)(ws + LO_OFF + ub))[lane];
    }
    const float bb = bo[h];
    float part = 0.f;
    #pragma unroll 2
    for (int mt = 0; mt < 4; ++mt) {
      const int row = mt*16 + n16;
      v4f acc = {0.f, 0.f, 0.f, 0.f};
      #pragma unroll
      for (int ks = 0; ks < KS2; ++ks) {
        v8s ah = *(const v8s*)(&sFA[row*FASTR + ks*32 + q*8]);
        v8s al = *(const v8s*)(&sFA[(64 + row)*FASTR + ks*32 + q*8]);
        acc = __builtin_amdgcn_mfma_f32_16x16x32_bf16(ah, bh[ks], acc, 0, 0, 0);
        acc = __builtin_amdgcn_mfma_f32_16x16x32_bf16(al, bh[ks], acc, 0, 0, 0);
        acc = __builtin_amdgcn_mfma_f32_16x16x32_bf16(ah, bl[ks], acc, 0, 0, 0);
      }
      #pragma unroll
      for (int r = 0; r < 4; ++r) {
        int node = sSorted[mt*16 + q*4 + r];
        if (node >= 0 && sDeg[node] > 0) part += fast_tanh(acc[r] + bb);
      }
    }
    part += __shfl_xor(part, 16);
    part += __shfl_xor(part, 32);
    if (lane < 16) sPart[h] = part;
  }
  __syncthreads();

  // ---- P9: final FC + sigmoid (parallel: 96 threads, 16 FMAs each, reduce) ----
  if (t < 96) {
    const int c = t >> 3, s = t & 7;
    float acc = 0.f;
    #pragma unroll
    for (int i = 0; i < 16; ++i) {
      int ii = s*16 + i;
      acc = fmaf(sPart[ii], Wfc[ii*CC + c], acc);
    }
    sRed[t] = acc;
  }
  __syncthreads();
  if (t < CC) {
    float acc = bfc[t];
    #pragma unroll
    for (int s = 0; s < 8; ++s) acc += sRed[t*8 + s];
    out[b*CC + t] = 1.f / (1.f + __expf(-acc));
  }
}

extern "C" void kernel_launch(void* const* d_in, const int* in_sizes, int n_in,
                              void* d_out, int out_size, void* d_ws, size_t ws_size,
                              hipStream_t stream) {
  const float* atoms = (const float*)d_in[0];
  const float* bonds = (const float*)d_in[1];
  const int*   edges = (const int*)d_in[2];
  const float* W1  = (const float*)d_in[3];
  const float* b1  = (const float*)d_in[4];
  const float* W2  = (const float*)d_in[5];
  const float* b2  = (const float*)d_in[6];
  const float* Wo  = (const float*)d_in[7];
  const float* bo  = (const float*)d_in[8];
  const float* Wfc = (const float*)d_in[9];
  const float* bfc = (const float*)d_in[10];
  float* out = (float*)d_out;
  u16* ws = (u16*)d_ws;

  prep_kernel<<<TOT_UNITS, 64, 0, stream>>>(W1, W2, Wo, ws);
  ngfp_kernel<<<NB, T, 0, stream>>>(atoms, bonds, edges, b1, b2, bo, Wfc, bfc, ws, out);
}